// Round 2
// baseline (471.765 us; speedup 1.0000x reference)
//
#include <hip/hip_runtime.h>
#include <hip/hip_bf16.h>
#include <cstdint>
#include <cstddef>

#define DEV static __device__ __forceinline__

typedef float f32x4 __attribute__((ext_vector_type(4)));
typedef __bf16 bf16x8 __attribute__((ext_vector_type(8)));

union B8 {
  uint4 u4;
  uint32_t u[4];
  unsigned short s[8];
  bf16x8 v;
};

DEV unsigned short f2bf(float f) {
  union { float f; uint32_t u; } x; x.f = f;
  uint32_t r = x.u + 0x7fffu + ((x.u >> 16) & 1u);
  return (unsigned short)(r >> 16);
}

DEV f32x4 mfma_bf16(bf16x8 a, bf16x8 b, f32x4 c) {
  return __builtin_amdgcn_mfma_f32_16x16x32_bf16(a, b, c, 0, 0, 0);
}

// ---------------------------------------------------------------------------
// C = A[M,K] @ B[N,K]^T + bias[N]
// OUT_MODE 0: bf16 row-major [M,N]
// OUT_MODE 1: bf16 "Vt" layout [B=2,H=16,hd=64,S=2048] (row=b*2048+s, col=h*64+d)
// OUT_MODE 2: f32 row-major [M,N]
// A_BF16: A is bf16 (row-major [M,K]); else fp32.
// Tiles: 128x128, BK=64, 256 threads (4 waves, 2x2), 16x16x32 bf16 MFMA.
// LDS rows are 128B; 16B-slot XOR swizzle (slot ^= row&7) -> conflict-free reads.
// ---------------------------------------------------------------------------
template<int OUT_MODE, bool A_BF16>
__global__ __launch_bounds__(256, 2)
void gemm_bt(const void* __restrict__ Av, const float* __restrict__ Bw,
             const float* __restrict__ bias, void* __restrict__ Cv,
             int M, int N, int K) {
  __shared__ __align__(16) unsigned short As[128 * 64];
  __shared__ __align__(16) unsigned short Bs[128 * 64];
  const int nbn = N >> 7;
  const int mb = blockIdx.x / nbn, nb = blockIdx.x % nbn;
  const int tid = threadIdx.x;
  const int lane = tid & 63, w = tid >> 6;
  const int wm = w >> 1, wn = w & 1;
  f32x4 acc[4][4] = {};

  const int nkt = K >> 6;
  for (int kt = 0; kt < nkt; ++kt) {
    __syncthreads();
#pragma unroll
    for (int i = 0; i < 4; ++i) {
      const int chunk = tid + (i << 8);      // 0..1023 : 128 rows x 8 slots
      const int r = chunk >> 3, c8 = chunk & 7;
      const int slot = c8 ^ (r & 7);
      B8 pa;
      if (A_BF16) {
        pa.u4 = *(const uint4*)((const unsigned short*)Av +
                 (size_t)(mb * 128 + r) * K + (kt << 6) + (c8 << 3));
      } else {
        const float* srcA = (const float*)Av +
                 (size_t)(mb * 128 + r) * K + (kt << 6) + (c8 << 3);
        float4 a0 = *(const float4*)srcA;
        float4 a1 = *(const float4*)(srcA + 4);
        pa.u[0] = f2bf(a0.x) | ((uint32_t)f2bf(a0.y) << 16);
        pa.u[1] = f2bf(a0.z) | ((uint32_t)f2bf(a0.w) << 16);
        pa.u[2] = f2bf(a1.x) | ((uint32_t)f2bf(a1.y) << 16);
        pa.u[3] = f2bf(a1.z) | ((uint32_t)f2bf(a1.w) << 16);
      }
      *(uint4*)&As[(r << 6) + (slot << 3)] = pa.u4;

      const float* srcB = Bw + (size_t)(nb * 128 + r) * K + (kt << 6) + (c8 << 3);
      float4 b0 = *(const float4*)srcB;
      float4 b1 = *(const float4*)(srcB + 4);
      B8 pb;
      pb.u[0] = f2bf(b0.x) | ((uint32_t)f2bf(b0.y) << 16);
      pb.u[1] = f2bf(b0.z) | ((uint32_t)f2bf(b0.w) << 16);
      pb.u[2] = f2bf(b1.x) | ((uint32_t)f2bf(b1.y) << 16);
      pb.u[3] = f2bf(b1.z) | ((uint32_t)f2bf(b1.w) << 16);
      *(uint4*)&Bs[(r << 6) + (slot << 3)] = pb.u4;
    }
    __syncthreads();

    B8 af[4][2], bfr[4][2];
#pragma unroll
    for (int mi = 0; mi < 4; ++mi)
#pragma unroll
      for (int kk = 0; kk < 2; ++kk) {
        const int row = wm * 64 + mi * 16 + (lane & 15);
        const int slot = ((kk << 2) + (lane >> 4)) ^ (row & 7);
        af[mi][kk].u4 = *(const uint4*)&As[(row << 6) + (slot << 3)];
      }
#pragma unroll
    for (int ni = 0; ni < 4; ++ni)
#pragma unroll
      for (int kk = 0; kk < 2; ++kk) {
        const int row = wn * 64 + ni * 16 + (lane & 15);
        const int slot = ((kk << 2) + (lane >> 4)) ^ (row & 7);
        bfr[ni][kk].u4 = *(const uint4*)&Bs[(row << 6) + (slot << 3)];
      }
#pragma unroll
    for (int kk = 0; kk < 2; ++kk)
#pragma unroll
      for (int mi = 0; mi < 4; ++mi)
#pragma unroll
        for (int ni = 0; ni < 4; ++ni)
          acc[mi][ni] = mfma_bf16(af[mi][kk].v, bfr[ni][kk].v, acc[mi][ni]);
  }

  // epilogue: C/D layout col = lane&15, row = (lane>>4)*4 + r  [m89 verified]
#pragma unroll
  for (int ni = 0; ni < 4; ++ni) {
    const int col = nb * 128 + wn * 64 + ni * 16 + (lane & 15);
    const float bv = bias[col];
#pragma unroll
    for (int mi = 0; mi < 4; ++mi) {
#pragma unroll
      for (int r = 0; r < 4; ++r) {
        const int row = mb * 128 + wm * 64 + mi * 16 + (lane >> 4) * 4 + r;
        const float val = acc[mi][ni][r] + bv;
        if (OUT_MODE == 0) {
          ((unsigned short*)Cv)[(size_t)row * N + col] = f2bf(val);
        } else if (OUT_MODE == 1) {
          const int b = row >> 11, ss = row & 2047, hh = col >> 6, d = col & 63;
          ((unsigned short*)Cv)[((size_t)((b * 16 + hh) * 64 + d) << 11) + ss] = f2bf(val);
        } else {
          ((float*)Cv)[(size_t)row * N + col] = val;
        }
      }
    }
  }
}

// ---------------------------------------------------------------------------
// Causal flash attention with ALiBi. B=2,H=16,S=2048,hd=64. 4 waves/block,
// each wave owns 16 q rows, iterates KV tiles of 32. ZERO LDS.
// Swapped QK^T: mfma(A=K, B=Q) -> S^T[kv][q]; lane holds q = q0 + (lane&15),
// kv = kv0 + 16f + 4g + r (g=lane>>4). Softmax reduce: in-lane + shfl_xor 16,32.
// PV as mfma(A=V^T-frag, B=P^T-frag): P^T repacked in registers (lane's own
// 8 p-values, positional k-mapping phi(g,j) = (j>>2)*16 + g*4 + (j&3)); V^T
// loaded from Vt[d][s] at s = kv0+g*4 and kv0+16+g*4 (two 8B loads) -> same
// phi on both operands -> pairing-invariant. Output D2[d-off=g*4+r][q=lane&15]
// keeps q on lane&15 = same as softmax state -> shfl-free epilogue.
// ---------------------------------------------------------------------------
__global__ __launch_bounds__(256, 2)
void flash_alibi(const unsigned short* __restrict__ Qp,
                 const unsigned short* __restrict__ Kp,
                 const unsigned short* __restrict__ Vt,
                 unsigned short* __restrict__ At) {
  const int S = 2048, Dm = 1024;
  const int bid = blockIdx.x;            // b*512 + h*32 + qb
  const int qb = bid & 31, h = (bid >> 5) & 15, b = bid >> 9;
  const int tid = threadIdx.x, lane = tid & 63, w = tid >> 6;
  const int q0 = qb * 64 + w * 16;
  const float slope = exp2f(-(float)(h + 1));   // H=16 power-of-2 slopes

  const int qc = lane & 15;
  const int g = lane >> 4;
  const int qcol = q0 + qc;

  B8 qf[2];
  {
    const unsigned short* qbase = Qp + (size_t)(b * S + qcol) * Dm + h * 64 + g * 8;
    qf[0].u4 = *(const uint4*)qbase;
    qf[1].u4 = *(const uint4*)(qbase + 32);
  }

  const unsigned short* vhead = Vt + ((size_t)((b * 16 + h) * 64) << 11);

  f32x4 acc2[4] = {};        // [n][r] : d = n*16 + g*4 + r, q = q0 + qc
  float m_run = -1e30f, l_run = 0.f;

  const int ntile = ((q0 + 15) >> 5) + 1;
  for (int t = 0; t < ntile; ++t) {
    const int kv0 = t << 5;
    f32x4 sc[2] = {};
#pragma unroll
    for (int f = 0; f < 2; ++f) {
      const unsigned short* kbase =
          Kp + (size_t)(b * S + kv0 + f * 16 + qc) * Dm + h * 64 + g * 8;
      B8 kf0, kf1;
      kf0.u4 = *(const uint4*)kbase;
      kf1.u4 = *(const uint4*)(kbase + 32);
      sc[f] = mfma_bf16(kf0.v, qf[0].v, sc[f]);
      sc[f] = mfma_bf16(kf1.v, qf[1].v, sc[f]);
    }
    // mask + ALiBi; per-lane kv = kv0 + f*16 + g*4 + r, q = qcol
    float sv[2][4];
    float pmax = -1e30f;
#pragma unroll
    for (int f = 0; f < 2; ++f)
#pragma unroll
      for (int r = 0; r < 4; ++r) {
        const int kv = kv0 + f * 16 + g * 4 + r;
        float s = sc[f][r];
        s = (kv <= qcol) ? (s - slope * (float)(qcol - kv)) : -1e9f;
        sv[f][r] = s;
        pmax = fmaxf(pmax, s);
      }
    pmax = fmaxf(pmax, __shfl_xor(pmax, 16));
    pmax = fmaxf(pmax, __shfl_xor(pmax, 32));
    const float m_new = fmaxf(m_run, pmax);
    const float scale = __expf(m_run - m_new);
    float rsum = 0.f;
    unsigned short pb[2][4];
#pragma unroll
    for (int f = 0; f < 2; ++f)
#pragma unroll
      for (int r = 0; r < 4; ++r) {
        const float p = __expf(sv[f][r] - m_new);
        rsum += p;
        pb[f][r] = f2bf(p);
      }
    rsum += __shfl_xor(rsum, 16);
    rsum += __shfl_xor(rsum, 32);
    l_run = l_run * scale + rsum;
    m_run = m_new;

    // P^T fragment fully in registers: s[j] = P[q][kv0 + phi(g,j)],
    // phi(g,j) = (j>>2)*16 + g*4 + (j&3)
    B8 pfrag;
    pfrag.u[0] = pb[0][0] | ((uint32_t)pb[0][1] << 16);
    pfrag.u[1] = pb[0][2] | ((uint32_t)pb[0][3] << 16);
    pfrag.u[2] = pb[1][0] | ((uint32_t)pb[1][1] << 16);
    pfrag.u[3] = pb[1][2] | ((uint32_t)pb[1][3] << 16);

#pragma unroll
    for (int n = 0; n < 4; ++n) {
      acc2[n] = acc2[n] * scale;
      const unsigned short* vrow = vhead + ((size_t)(n * 16 + qc) << 11) + kv0 + g * 4;
      B8 vfrag;
      uint2 v0 = *(const uint2*)vrow;          // V[kv0+g*4 + 0..3][d-row]
      uint2 v1 = *(const uint2*)(vrow + 16);   // V[kv0+16+g*4 + 0..3][d-row]
      vfrag.u[0] = v0.x; vfrag.u[1] = v0.y;
      vfrag.u[2] = v1.x; vfrag.u[3] = v1.y;
      acc2[n] = mfma_bf16(vfrag.v, pfrag.v, acc2[n]);
    }
  }

  // epilogue: lane holds q = q0+qc (same as l_run), d = n*16 + g*4 + r
  const float rinv = 1.0f / l_run;
  unsigned short* obase = At + (size_t)(b * S + qcol) * Dm + h * 64;
#pragma unroll
  for (int n = 0; n < 4; ++n) {
    uint2 val;
    val.x = f2bf(acc2[n][0] * rinv) | ((uint32_t)f2bf(acc2[n][1] * rinv) << 16);
    val.y = f2bf(acc2[n][2] * rinv) | ((uint32_t)f2bf(acc2[n][3] * rinv) << 16);
    *(uint2*)(obase + n * 16 + g * 4) = val;
  }
}

extern "C" void kernel_launch(void* const* d_in, const int* in_sizes, int n_in,
                              void* d_out, int out_size, void* d_ws, size_t ws_size,
                              hipStream_t stream) {
  const float* q    = (const float*)d_in[0];
  const float* k    = (const float*)d_in[1];
  const float* v    = (const float*)d_in[2];
  // d_in[3] = causal mask, analytically known -> unused
  const float* wq_w = (const float*)d_in[4];
  const float* wq_b = (const float*)d_in[5];
  const float* wk_w = (const float*)d_in[6];
  const float* wk_b = (const float*)d_in[7];
  const float* wv_w = (const float*)d_in[8];
  const float* wv_b = (const float*)d_in[9];
  const float* ow   = (const float*)d_in[10];
  const float* ob   = (const float*)d_in[11];
  float* out = (float*)d_out;

  char* ws = (char*)d_ws;
  unsigned short* Qp = (unsigned short*)(ws);                  // 8MB bf16 [4096,1024]
  unsigned short* Kp = (unsigned short*)(ws + (8u << 20));     // 8MB
  unsigned short* Vt = (unsigned short*)(ws + (16u << 20));    // 8MB [B,H,64,2048]
  unsigned short* At = (unsigned short*)(ws + (24u << 20));    // 8MB [4096,1024]

  dim3 blk(256);
  gemm_bt<0, false><<<256, blk, 0, stream>>>(q, wq_w, wq_b, Qp, 4096, 1024, 1024);
  gemm_bt<0, false><<<256, blk, 0, stream>>>(k, wk_w, wk_b, Kp, 4096, 1024, 1024);
  gemm_bt<1, false><<<256, blk, 0, stream>>>(v, wv_w, wv_b, Vt, 4096, 1024, 1024);
  flash_alibi<<<1024, blk, 0, stream>>>(Qp, Kp, Vt, At);
  gemm_bt<2, true><<<256, blk, 0, stream>>>(At, ow, ob, out, 4096, 1024, 1024);
}

// Round 4
// 394.929 us; speedup vs baseline: 1.1946x; 1.1946x over previous
//
#include <hip/hip_runtime.h>
#include <hip/hip_bf16.h>
#include <cstdint>
#include <cstddef>

#define DEV static __device__ __forceinline__

typedef float f32x4 __attribute__((ext_vector_type(4)));
typedef __bf16 bf16x8 __attribute__((ext_vector_type(8)));
typedef __bf16 bf16x4 __attribute__((ext_vector_type(4)));

#define EXP2F(x) __builtin_amdgcn_exp2f(x)

union B8 {
  uint4 u4;
  uint32_t u[4];
  unsigned short s[8];
  bf16x8 v;
};
union B4 {
  uint2 u2;
  unsigned short s[4];
  bf16x4 v;
};

DEV unsigned short bfbits(float x) {
  union { __bf16 h; unsigned short s; } z; z.h = (__bf16)x; return z.s;
}
DEV uint32_t pk2(float x, float y) {
  union { __bf16 h[2]; uint32_t u; } z;
  z.h[0] = (__bf16)x; z.h[1] = (__bf16)y; return z.u;
}

DEV f32x4 mfma_bf16(bf16x8 a, bf16x8 b, f32x4 c) {
  return __builtin_amdgcn_mfma_f32_16x16x32_bf16(a, b, c, 0, 0, 0);
}

// ---------------------------------------------------------------------------
// C = A[M,K] @ B[N,K]^T + bias[N]
// OUT_MODE 0: bf16 row-major [M,N]
// OUT_MODE 1: bf16 "Vt" layout [B=2,H=16,hd=64,S=2048] (row=b*2048+s, col=h*64+d)
// OUT_MODE 2: f32 row-major [M,N]
// ---------------------------------------------------------------------------
template<int OUT_MODE, bool A_BF16>
__global__ __launch_bounds__(256, 2)
void gemm_bt(const void* __restrict__ Av, const float* __restrict__ Bw,
             const float* __restrict__ bias, void* __restrict__ Cv,
             int M, int N, int K) {
  __shared__ __align__(16) unsigned short As[128 * 64];
  __shared__ __align__(16) unsigned short Bs[128 * 64];
  const int nbn = N >> 7;
  const int mb = blockIdx.x / nbn, nb = blockIdx.x % nbn;
  const int tid = threadIdx.x;
  const int lane = tid & 63, w = tid >> 6;
  const int wm = w >> 1, wn = w & 1;
  f32x4 acc[4][4] = {};

  const int nkt = K >> 6;
  for (int kt = 0; kt < nkt; ++kt) {
    __syncthreads();
#pragma unroll
    for (int i = 0; i < 4; ++i) {
      const int chunk = tid + (i << 8);      // 0..1023 : 128 rows x 8 slots
      const int r = chunk >> 3, c8 = chunk & 7;
      const int slot = c8 ^ (r & 7);
      B8 pa;
      if (A_BF16) {
        pa.u4 = *(const uint4*)((const unsigned short*)Av +
                 (size_t)(mb * 128 + r) * K + (kt << 6) + (c8 << 3));
      } else {
        const float* srcA = (const float*)Av +
                 (size_t)(mb * 128 + r) * K + (kt << 6) + (c8 << 3);
        float4 a0 = *(const float4*)srcA;
        float4 a1 = *(const float4*)(srcA + 4);
        pa.u[0] = pk2(a0.x, a0.y); pa.u[1] = pk2(a0.z, a0.w);
        pa.u[2] = pk2(a1.x, a1.y); pa.u[3] = pk2(a1.z, a1.w);
      }
      *(uint4*)&As[(r << 6) + (slot << 3)] = pa.u4;

      const float* srcB = Bw + (size_t)(nb * 128 + r) * K + (kt << 6) + (c8 << 3);
      float4 b0 = *(const float4*)srcB;
      float4 b1 = *(const float4*)(srcB + 4);
      B8 pb;
      pb.u[0] = pk2(b0.x, b0.y); pb.u[1] = pk2(b0.z, b0.w);
      pb.u[2] = pk2(b1.x, b1.y); pb.u[3] = pk2(b1.z, b1.w);
      *(uint4*)&Bs[(r << 6) + (slot << 3)] = pb.u4;
    }
    __syncthreads();

    B8 af[4][2], bfr[4][2];
#pragma unroll
    for (int mi = 0; mi < 4; ++mi)
#pragma unroll
      for (int kk = 0; kk < 2; ++kk) {
        const int row = wm * 64 + mi * 16 + (lane & 15);
        const int slot = ((kk << 2) + (lane >> 4)) ^ (row & 7);
        af[mi][kk].u4 = *(const uint4*)&As[(row << 6) + (slot << 3)];
      }
#pragma unroll
    for (int ni = 0; ni < 4; ++ni)
#pragma unroll
      for (int kk = 0; kk < 2; ++kk) {
        const int row = wn * 64 + ni * 16 + (lane & 15);
        const int slot = ((kk << 2) + (lane >> 4)) ^ (row & 7);
        bfr[ni][kk].u4 = *(const uint4*)&Bs[(row << 6) + (slot << 3)];
      }
#pragma unroll
    for (int kk = 0; kk < 2; ++kk)
#pragma unroll
      for (int mi = 0; mi < 4; ++mi)
#pragma unroll
        for (int ni = 0; ni < 4; ++ni)
          acc[mi][ni] = mfma_bf16(af[mi][kk].v, bfr[ni][kk].v, acc[mi][ni]);
  }

  // epilogue: C/D layout col = lane&15, row = (lane>>4)*4 + r  [m89 verified]
#pragma unroll
  for (int ni = 0; ni < 4; ++ni) {
    const int col = nb * 128 + wn * 64 + ni * 16 + (lane & 15);
    const float bv = bias[col];
#pragma unroll
    for (int mi = 0; mi < 4; ++mi) {
#pragma unroll
      for (int r = 0; r < 4; ++r) {
        const int row = mb * 128 + wm * 64 + mi * 16 + (lane >> 4) * 4 + r;
        const float val = acc[mi][ni][r] + bv;
        if (OUT_MODE == 0) {
          ((unsigned short*)Cv)[(size_t)row * N + col] = bfbits(val);
        } else if (OUT_MODE == 1) {
          const int b = row >> 11, ss = row & 2047, hh = col >> 6, d = col & 63;
          ((unsigned short*)Cv)[((size_t)((b * 16 + hh) * 64 + d) << 11) + ss] = bfbits(val);
        } else {
          ((float*)Cv)[(size_t)row * N + col] = val;
        }
      }
    }
  }
}

// ---------------------------------------------------------------------------
// Causal flash attention + ALiBi. B=2,H=16,S=2048,hd=64.
// Zero LDS / zero barriers; all staging in registers.
// Grid 512 = b(2) x h(16) x pair(16). Pair p: strips sL=p, sH=31-p (64 rows).
// Wave w owns TWO 16-row q-fragments: qA0=sL*64+w*16, qB0=sH*64+w*16 ->
// every wave does exactly (sL+1)+(sH+1)=34 KV-tiles of 64 -> perfect balance,
// and K/V loads are shared between the two fragments.
// Swapped QK^T: mfma(A=K,B=Q); lane holds q=lane&15, kv=kv0+16f+4g+r.
// Softmax: ein = log2e*(s-m) built via one fma/score (ALiBi folded into the
// constant); T13 defer-max: lane-local emax + __all check, cross-lane max
// reduce ONLY on trigger; denominator kept per-lane (l_loc), reduced once in
// the epilogue (2 shuffles total per fragment).
// PV: mfma(A=V^T frag from Vt[d][s], B=P^T packed in-register), positional
// k-mapping identical on both operands. K double-buffered (prefetch t+1
// before softmax of t); V issued at tile top, consumed post-softmax.
// ---------------------------------------------------------------------------
__global__ __launch_bounds__(256, 2)
void flash_alibi(const unsigned short* __restrict__ Qp,
                 const unsigned short* __restrict__ Kp,
                 const unsigned short* __restrict__ Vt,
                 unsigned short* __restrict__ At) {
  const int S = 2048, Dm = 1024;
  const int bid = blockIdx.x;            // b*256 + h*16 + p
  const int p = bid & 15, h = (bid >> 4) & 15, b = bid >> 8;
  const int lane = threadIdx.x & 63, w = threadIdx.x >> 6;
  const int sL = p, sH = 31 - p;
  const int qc = lane & 15, g = lane >> 4;
  const int qA0 = sL * 64 + w * 16, qB0 = sH * 64 + w * 16;
  const int qAcol = qA0 + qc, qBcol = qB0 + qc;
  const float slope = exp2f(-(float)(h + 1));   // H=16 power-of-2 slopes
  const float L2E = 1.44269504f;
  const float ls1 = L2E * slope;
  const float THR = 11.54f;                      // 8 * log2(e)

  const size_t bS = (size_t)b * S;
  const int hoff = h * 64;

  B8 qfA[2], qfB[2];
  {
    const unsigned short* qa = Qp + (bS + qAcol) * Dm + hoff + g * 8;
    qfA[0].u4 = *(const uint4*)qa; qfA[1].u4 = *(const uint4*)(qa + 32);
    const unsigned short* qb = Qp + (bS + qBcol) * Dm + hoff + g * 8;
    qfB[0].u4 = *(const uint4*)qb; qfB[1].u4 = *(const uint4*)(qb + 32);
  }
  const unsigned short* vhead = Vt + (((size_t)(b * 16 + h) * 64) << 11);
  const unsigned short* khead = Kp + (bS + qc) * Dm + hoff + g * 8;

  f32x4 accA[4] = {}, accB[4] = {};
  float mA = 0.f, lA = 0.f, mB = 0.f, lB = 0.f;
  const float abqA = slope * (float)(g * 4 - qAcol);
  const float abqB = slope * (float)(g * 4 - qBcol);

  const int ntile = sH + 1;
  uint2 Vb[4][4];
  B8 Ka[8], Kb[8];

#define KLOAD(KX, TT) do { if ((TT) < ntile) {                                 \
    const unsigned short* kp_ = khead + (((size_t)(TT)) << 6) * Dm;            \
    _Pragma("unroll")                                                          \
    for (int f_ = 0; f_ < 4; ++f_) {                                           \
      KX[2*f_].u4   = *(const uint4*)(kp_ + (size_t)(f_*16) * Dm);             \
      KX[2*f_+1].u4 = *(const uint4*)(kp_ + (size_t)(f_*16) * Dm + 32);        \
    } } } while (0)

#define VLOAD(KV0) do {                                                        \
    _Pragma("unroll")                                                          \
    for (int n_ = 0; n_ < 4; ++n_) {                                           \
      const unsigned short* vr_ =                                              \
          vhead + (((size_t)(n_*16 + qc)) << 11) + (KV0) + g * 4;              \
      Vb[n_][0] = *(const uint2*)vr_;        Vb[n_][1] = *(const uint2*)(vr_ + 16); \
      Vb[n_][2] = *(const uint2*)(vr_ + 32); Vb[n_][3] = *(const uint2*)(vr_ + 48); \
    } } while (0)

#define FRAG(KC, QF, ACC, MS, LS, ABQ, QCOL, MASKED) do {                      \
    f32x4 sc_[4] = {};                                                         \
    _Pragma("unroll")                                                          \
    for (int f_ = 0; f_ < 4; ++f_) {                                           \
      sc_[f_] = mfma_bf16(KC[2*f_].v,   QF[0].v, sc_[f_]);                     \
      sc_[f_] = mfma_bf16(KC[2*f_+1].v, QF[1].v, sc_[f_]);                     \
    }                                                                          \
    const float cb_ = (fmaf(slope, kv0f, (ABQ)) - (MS)) * L2E;                 \
    float ein_[4][4]; float emax_ = -1e30f;                                    \
    _Pragma("unroll")                                                          \
    for (int f_ = 0; f_ < 4; ++f_) {                                           \
      const float cf_ = cb_ + (float)(16 * f_) * ls1;                          \
      _Pragma("unroll")                                                        \
      for (int r_ = 0; r_ < 4; ++r_) {                                         \
        float e_ = fmaf(sc_[f_][r_], L2E, cf_ + (float)r_ * ls1);              \
        if (MASKED) {                                                          \
          const int kv_ = kv0 + f_*16 + g*4 + r_;                              \
          if (kv_ > (QCOL)) e_ = -1e30f;                                       \
        }                                                                      \
        ein_[f_][r_] = e_; emax_ = fmaxf(emax_, e_);                           \
      }                                                                        \
    }                                                                          \
    if (!__all(emax_ <= THR)) {                                                \
      float er_ = fmaxf(emax_, __shfl_xor(emax_, 16));                         \
      er_ = fmaxf(er_, __shfl_xor(er_, 32));                                   \
      er_ = fmaxf(er_, 0.f);                                                   \
      (MS) += er_ * 0.69314718f;                                               \
      const float sfac_ = EXP2F(-er_);                                         \
      (LS) *= sfac_;                                                           \
      _Pragma("unroll") for (int n_ = 0; n_ < 4; ++n_) ACC[n_] = ACC[n_] * sfac_; \
      _Pragma("unroll") for (int f_ = 0; f_ < 4; ++f_)                         \
        _Pragma("unroll") for (int r_ = 0; r_ < 4; ++r_) ein_[f_][r_] -= er_;  \
    }                                                                          \
    B8 pf0_, pf1_; float lsum_ = 0.f;                                          \
    _Pragma("unroll")                                                          \
    for (int f_ = 0; f_ < 4; ++f_) {                                           \
      _Pragma("unroll")                                                        \
      for (int r_ = 0; r_ < 4; ++r_) {                                         \
        const float p_ = EXP2F(ein_[f_][r_]);                                  \
        lsum_ += p_;                                                           \
        if (f_ == 0)      pf0_.v[r_]     = (__bf16)p_;                         \
        else if (f_ == 1) pf0_.v[4 + r_] = (__bf16)p_;                         \
        else if (f_ == 2) pf1_.v[r_]     = (__bf16)p_;                         \
        else              pf1_.v[4 + r_] = (__bf16)p_;                         \
      }                                                                        \
    }                                                                          \
    (LS) += lsum_;                                                             \
    _Pragma("unroll")                                                          \
    for (int n_ = 0; n_ < 4; ++n_) {                                           \
      B8 v0_, v1_;                                                             \
      v0_.u[0] = Vb[n_][0].x; v0_.u[1] = Vb[n_][0].y;                          \
      v0_.u[2] = Vb[n_][1].x; v0_.u[3] = Vb[n_][1].y;                          \
      v1_.u[0] = Vb[n_][2].x; v1_.u[1] = Vb[n_][2].y;                          \
      v1_.u[2] = Vb[n_][3].x; v1_.u[3] = Vb[n_][3].y;                          \
      ACC[n_] = mfma_bf16(v0_.v, pf0_.v, ACC[n_]);                             \
      ACC[n_] = mfma_bf16(v1_.v, pf1_.v, ACC[n_]);                             \
    }                                                                          \
  } while (0)

#define STEP(KC, KN, TT) do {                                                  \
    const int t_ = (TT);                                                       \
    const int kv0 = t_ << 6;                                                   \
    const float kv0f = (float)kv0;                                             \
    VLOAD(kv0);                                                                \
    KLOAD(KN, t_ + 1);                                                         \
    FRAG(KC, qfB, accB, mB, lB, abqB, qBcol, (t_ == sH));                      \
    if (t_ <= sL) FRAG(KC, qfA, accA, mA, lA, abqA, qAcol, (t_ == sL));        \
  } while (0)

  KLOAD(Ka, 0);
  int t = 0;
  for (; t + 1 < ntile; t += 2) {
    STEP(Ka, Kb, t);
    STEP(Kb, Ka, t + 1);
  }
  if (t < ntile) STEP(Ka, Kb, t);

#define EPI(ACC, LS, QCOL) do {                                                \
    float lt_ = (LS) + __shfl_xor((LS), 16);                                   \
    lt_ += __shfl_xor(lt_, 32);                                                \
    const float ri_ = 1.0f / lt_;                                              \
    unsigned short* ob_ = At + (bS + (QCOL)) * Dm + hoff;                      \
    _Pragma("unroll")                                                          \
    for (int n_ = 0; n_ < 4; ++n_) {                                           \
      B4 ov_;                                                                  \
      ov_.v[0] = (__bf16)(ACC[n_][0] * ri_);                                   \
      ov_.v[1] = (__bf16)(ACC[n_][1] * ri_);                                   \
      ov_.v[2] = (__bf16)(ACC[n_][2] * ri_);                                   \
      ov_.v[3] = (__bf16)(ACC[n_][3] * ri_);                                   \
      *(uint2*)(ob_ + n_ * 16 + g * 4) = ov_.u2;                               \
    } } while (0)

  EPI(accA, lA, qAcol);
  EPI(accB, lB, qBcol);
}

extern "C" void kernel_launch(void* const* d_in, const int* in_sizes, int n_in,
                              void* d_out, int out_size, void* d_ws, size_t ws_size,
                              hipStream_t stream) {
  const float* q    = (const float*)d_in[0];
  const float* k    = (const float*)d_in[1];
  const float* v    = (const float*)d_in[2];
  // d_in[3] = causal mask, analytically known -> unused
  const float* wq_w = (const float*)d_in[4];
  const float* wq_b = (const float*)d_in[5];
  const float* wk_w = (const float*)d_in[6];
  const float* wk_b = (const float*)d_in[7];
  const float* wv_w = (const float*)d_in[8];
  const float* wv_b = (const float*)d_in[9];
  const float* ow   = (const float*)d_in[10];
  const float* ob   = (const float*)d_in[11];
  float* out = (float*)d_out;

  char* ws = (char*)d_ws;
  unsigned short* Qp = (unsigned short*)(ws);                  // 8MB bf16 [4096,1024]
  unsigned short* Kp = (unsigned short*)(ws + (8u << 20));     // 8MB
  unsigned short* Vt = (unsigned short*)(ws + (16u << 20));    // 8MB [B,H,64,2048]
  unsigned short* At = (unsigned short*)(ws + (24u << 20));    // 8MB [4096,1024]

  dim3 blk(256);
  gemm_bt<0, false><<<256, blk, 0, stream>>>(q, wq_w, wq_b, Qp, 4096, 1024, 1024);
  gemm_bt<0, false><<<256, blk, 0, stream>>>(k, wk_w, wk_b, Kp, 4096, 1024, 1024);
  gemm_bt<1, false><<<256, blk, 0, stream>>>(v, wv_w, wv_b, Vt, 4096, 1024, 1024);
  flash_alibi<<<512, blk, 0, stream>>>(Qp, Kp, Vt, At);
  gemm_bt<2, true><<<256, blk, 0, stream>>>(At, ow, ob, out, 4096, 1024, 1024);
}

// Round 5
// 268.039 us; speedup vs baseline: 1.7601x; 1.4734x over previous
//
#include <hip/hip_runtime.h>
#include <hip/hip_bf16.h>
#include <cstdint>
#include <cstddef>

#define DEV static __device__ __forceinline__

typedef float f32x4 __attribute__((ext_vector_type(4)));
typedef __bf16 bf16x8 __attribute__((ext_vector_type(8)));
typedef __bf16 bf16x4 __attribute__((ext_vector_type(4)));

#define EXP2F(x) __builtin_amdgcn_exp2f(x)

union B8 {
  uint4 u4;
  uint32_t u[4];
  unsigned short s[8];
  bf16x8 v;
};
union B4 {
  uint2 u2;
  unsigned short s[4];
  bf16x4 v;
};

DEV unsigned short bfbits(float x) {
  union { __bf16 h; unsigned short s; } z; z.h = (__bf16)x; return z.s;
}
DEV uint32_t pk2(float x, float y) {
  union { __bf16 h[2]; uint32_t u; } z;
  z.h[0] = (__bf16)x; z.h[1] = (__bf16)y; return z.u;
}

DEV f32x4 mfma_bf16(bf16x8 a, bf16x8 b, f32x4 c) {
  return __builtin_amdgcn_mfma_f32_16x16x32_bf16(a, b, c, 0, 0, 0);
}

// ---------------------------------------------------------------------------
// C = A[M,K] @ B[N,K]^T + bias[N]   (unchanged from r4)
// OUT_MODE 0: bf16 row-major [M,N]
// OUT_MODE 1: bf16 "Vt" layout [B=2,H=16,hd=64,S=2048] (row=b*2048+s, col=h*64+d)
// OUT_MODE 2: f32 row-major [M,N]
// ---------------------------------------------------------------------------
template<int OUT_MODE, bool A_BF16>
__global__ __launch_bounds__(256, 2)
void gemm_bt(const void* __restrict__ Av, const float* __restrict__ Bw,
             const float* __restrict__ bias, void* __restrict__ Cv,
             int M, int N, int K) {
  __shared__ __align__(16) unsigned short As[128 * 64];
  __shared__ __align__(16) unsigned short Bs[128 * 64];
  const int nbn = N >> 7;
  const int mb = blockIdx.x / nbn, nb = blockIdx.x % nbn;
  const int tid = threadIdx.x;
  const int lane = tid & 63, w = tid >> 6;
  const int wm = w >> 1, wn = w & 1;
  f32x4 acc[4][4] = {};

  const int nkt = K >> 6;
  for (int kt = 0; kt < nkt; ++kt) {
    __syncthreads();
#pragma unroll
    for (int i = 0; i < 4; ++i) {
      const int chunk = tid + (i << 8);      // 0..1023 : 128 rows x 8 slots
      const int r = chunk >> 3, c8 = chunk & 7;
      const int slot = c8 ^ (r & 7);
      B8 pa;
      if (A_BF16) {
        pa.u4 = *(const uint4*)((const unsigned short*)Av +
                 (size_t)(mb * 128 + r) * K + (kt << 6) + (c8 << 3));
      } else {
        const float* srcA = (const float*)Av +
                 (size_t)(mb * 128 + r) * K + (kt << 6) + (c8 << 3);
        float4 a0 = *(const float4*)srcA;
        float4 a1 = *(const float4*)(srcA + 4);
        pa.u[0] = pk2(a0.x, a0.y); pa.u[1] = pk2(a0.z, a0.w);
        pa.u[2] = pk2(a1.x, a1.y); pa.u[3] = pk2(a1.z, a1.w);
      }
      *(uint4*)&As[(r << 6) + (slot << 3)] = pa.u4;

      const float* srcB = Bw + (size_t)(nb * 128 + r) * K + (kt << 6) + (c8 << 3);
      float4 b0 = *(const float4*)srcB;
      float4 b1 = *(const float4*)(srcB + 4);
      B8 pb;
      pb.u[0] = pk2(b0.x, b0.y); pb.u[1] = pk2(b0.z, b0.w);
      pb.u[2] = pk2(b1.x, b1.y); pb.u[3] = pk2(b1.z, b1.w);
      *(uint4*)&Bs[(r << 6) + (slot << 3)] = pb.u4;
    }
    __syncthreads();

    B8 af[4][2], bfr[4][2];
#pragma unroll
    for (int mi = 0; mi < 4; ++mi)
#pragma unroll
      for (int kk = 0; kk < 2; ++kk) {
        const int row = wm * 64 + mi * 16 + (lane & 15);
        const int slot = ((kk << 2) + (lane >> 4)) ^ (row & 7);
        af[mi][kk].u4 = *(const uint4*)&As[(row << 6) + (slot << 3)];
      }
#pragma unroll
    for (int ni = 0; ni < 4; ++ni)
#pragma unroll
      for (int kk = 0; kk < 2; ++kk) {
        const int row = wn * 64 + ni * 16 + (lane & 15);
        const int slot = ((kk << 2) + (lane >> 4)) ^ (row & 7);
        bfr[ni][kk].u4 = *(const uint4*)&Bs[(row << 6) + (slot << 3)];
      }
#pragma unroll
    for (int kk = 0; kk < 2; ++kk)
#pragma unroll
      for (int mi = 0; mi < 4; ++mi)
#pragma unroll
        for (int ni = 0; ni < 4; ++ni)
          acc[mi][ni] = mfma_bf16(af[mi][kk].v, bfr[ni][kk].v, acc[mi][ni]);
  }

  // epilogue: C/D layout col = lane&15, row = (lane>>4)*4 + r  [m89 verified]
#pragma unroll
  for (int ni = 0; ni < 4; ++ni) {
    const int col = nb * 128 + wn * 64 + ni * 16 + (lane & 15);
    const float bv = bias[col];
#pragma unroll
    for (int mi = 0; mi < 4; ++mi) {
#pragma unroll
      for (int r = 0; r < 4; ++r) {
        const int row = mb * 128 + wm * 64 + mi * 16 + (lane >> 4) * 4 + r;
        const float val = acc[mi][ni][r] + bv;
        if (OUT_MODE == 0) {
          ((unsigned short*)Cv)[(size_t)row * N + col] = bfbits(val);
        } else if (OUT_MODE == 1) {
          const int b = row >> 11, ss = row & 2047, hh = col >> 6, d = col & 63;
          ((unsigned short*)Cv)[((size_t)((b * 16 + hh) * 64 + d) << 11) + ss] = bfbits(val);
        } else {
          ((float*)Cv)[(size_t)row * N + col] = val;
        }
      }
    }
  }
}

// ---------------------------------------------------------------------------
// Causal flash attention + ALiBi v3: LDS-staged K/V shared by 4 waves.
// Grid 1024 = z(32: b*16+h) x y(32); strip s = (y+z)&31 (mixes strip lengths
// across co-resident blocks). Block = one 64-row strip, 4 waves x 16 rows.
// Per tile (KVBLK=64): all threads cooperatively stage K-tile [64 kv][64 hd]
// and V-tile [64 d][64 s] into LDS (coalesced 16B loads, XOR-swizzled
// granule ^= row&7 -> conflict-free ds_read_b128). T14 split: global loads
// for t+1 issue before compute of t, ds_write after barrier.
// Swapped QK^T: mfma(A=K,B=Q); lane q=lane&15, kv=kv0+16f+4g+r. Defer-max
// softmax (lane-local, cross-lane reduce only on trigger), per-lane l,
// in-register P^T; PV: mfma(A=V^T,B=P^T). Masked diagonal tile peeled.
// ---------------------------------------------------------------------------
__global__ __launch_bounds__(256, 4)
void flash_alibi(const unsigned short* __restrict__ Qp,
                 const unsigned short* __restrict__ Kp,
                 const unsigned short* __restrict__ Vt,
                 unsigned short* __restrict__ At) {
  const int S = 2048, Dm = 1024;
  const int bid = blockIdx.x;
  const int z = bid >> 5, y = bid & 31;
  const int s = (y + z) & 31;
  const int h = z & 15, b = z >> 4;
  const int tid = threadIdx.x, lane = tid & 63, w = tid >> 6;
  const int qc = lane & 15, g = lane >> 4;
  const int q0 = s * 64 + w * 16;
  const int qcol = q0 + qc;
  const float slope = exp2f(-(float)(h + 1));   // H=16 power-of-2 slopes
  const float L2E = 1.44269504f;
  const float ls1 = L2E * slope;
  const float THR = 11.54f;                      // 8 * log2(e)
  const size_t bS = (size_t)b * S;
  const int hoff = h * 64;
  const int ntile = s + 1;

  __shared__ __align__(16) unsigned short Ks[64 * 64];   // 8KB [kv][hd swz]
  __shared__ __align__(16) unsigned short Vs[64 * 64];   // 8KB [d][s swz]

  // Q fragment (global, per-lane)
  B8 qf[2];
  {
    const unsigned short* qa = Qp + (bS + qcol) * Dm + hoff + g * 8;
    qf[0].u4 = *(const uint4*)qa; qf[1].u4 = *(const uint4*)(qa + 32);
  }

  // --- staging geometry: thread stages 2x16B per array ---
  const int srow = tid >> 2;                 // 0..63
  const int sg0 = (tid & 3) * 2;             // granule (16B unit) 0..6 even
  const int ssw = srow & 7;
  const unsigned short* kg0 = Kp + (bS + srow) * Dm + hoff + sg0 * 8;
  const unsigned short* vg0 = Vt + (((size_t)((b * 16 + h) * 64 + srow)) << 11) + sg0 * 8;
  unsigned short* kw0 = &Ks[srow * 64 + ((sg0 ^ ssw) << 3)];
  unsigned short* kw1 = &Ks[srow * 64 + (((sg0 + 1) ^ ssw) << 3)];
  unsigned short* vw0 = &Vs[srow * 64 + ((sg0 ^ ssw) << 3)];
  unsigned short* vw1 = &Vs[srow * 64 + (((sg0 + 1) ^ ssw) << 3)];
  uint4 krA, krB, vrA, vrB;

#define SLOAD(TT) do {                                                         \
    const unsigned short* kp_ = kg0 + (((size_t)(TT)) << 6) * Dm;              \
    krA = *(const uint4*)kp_; krB = *(const uint4*)(kp_ + 8);                  \
    const unsigned short* vp_ = vg0 + ((TT) << 6);                             \
    vrA = *(const uint4*)vp_; vrB = *(const uint4*)(vp_ + 8);                  \
  } while (0)
#define SWRITE() do {                                                          \
    *(uint4*)kw0 = krA; *(uint4*)kw1 = krB;                                    \
    *(uint4*)vw0 = vrA; *(uint4*)vw1 = vrB;                                    \
  } while (0)

  // --- LDS read bases (constant across tiles) ---
  const int sw = qc & 7;
  const unsigned short* krd0 = &Ks[qc * 64 + ((g ^ sw) << 3)];          // +f*1024
  const unsigned short* krd1 = &Ks[qc * 64 + (((g ^ sw) ^ 4) << 3)];
  const unsigned short* vrd[4];
#pragma unroll
  for (int j = 0; j < 4; ++j)
    vrd[j] = &Vs[qc * 64 + ((((2 * j) + (g >> 1)) ^ sw) << 3) + (g & 1) * 4];  // +n*1024

  f32x4 acc[4] = {};
  float m_run = 0.f, l_run = 0.f;
  const float abq = slope * (float)(g * 4 - qcol);

#define FRAGX(KV0, MASKED) do {                                                \
    const float kv0f = (float)(KV0);                                           \
    f32x4 sc_[4] = {};                                                         \
    _Pragma("unroll")                                                          \
    for (int f_ = 0; f_ < 4; ++f_) {                                           \
      B8 k0_, k1_;                                                             \
      k0_.u4 = *(const uint4*)(krd0 + f_ * 1024);                              \
      k1_.u4 = *(const uint4*)(krd1 + f_ * 1024);                              \
      sc_[f_] = mfma_bf16(k0_.v, qf[0].v, sc_[f_]);                            \
      sc_[f_] = mfma_bf16(k1_.v, qf[1].v, sc_[f_]);                            \
    }                                                                          \
    const float cb_ = (fmaf(slope, kv0f, abq) - m_run) * L2E;                  \
    float ein_[4][4]; float emax_ = -1e30f;                                    \
    _Pragma("unroll")                                                          \
    for (int f_ = 0; f_ < 4; ++f_) {                                           \
      const float cf_ = cb_ + (float)(16 * f_) * ls1;                          \
      _Pragma("unroll")                                                        \
      for (int r_ = 0; r_ < 4; ++r_) {                                         \
        float e_ = fmaf(sc_[f_][r_], L2E, cf_ + (float)r_ * ls1);              \
        if (MASKED) {                                                          \
          const int kv_ = (KV0) + f_ * 16 + g * 4 + r_;                        \
          if (kv_ > qcol) e_ = -1e30f;                                         \
        }                                                                      \
        ein_[f_][r_] = e_; emax_ = fmaxf(emax_, e_);                           \
      }                                                                        \
    }                                                                          \
    if (!__all(emax_ <= THR)) {                                                \
      float er_ = fmaxf(emax_, __shfl_xor(emax_, 16));                         \
      er_ = fmaxf(er_, __shfl_xor(er_, 32));                                   \
      er_ = fmaxf(er_, 0.f);                                                   \
      m_run += er_ * 0.69314718f;                                              \
      const float sfac_ = EXP2F(-er_);                                         \
      l_run *= sfac_;                                                          \
      _Pragma("unroll") for (int n_ = 0; n_ < 4; ++n_) acc[n_] = acc[n_] * sfac_; \
      _Pragma("unroll") for (int f_ = 0; f_ < 4; ++f_)                         \
        _Pragma("unroll") for (int r_ = 0; r_ < 4; ++r_) ein_[f_][r_] -= er_;  \
    }                                                                          \
    B8 pf0_, pf1_; float lsum_ = 0.f;                                          \
    _Pragma("unroll")                                                          \
    for (int f_ = 0; f_ < 4; ++f_) {                                           \
      _Pragma("unroll")                                                        \
      for (int r_ = 0; r_ < 4; ++r_) {                                         \
        const float p_ = EXP2F(ein_[f_][r_]);                                  \
        lsum_ += p_;                                                           \
        if (f_ == 0)      pf0_.v[r_]     = (__bf16)p_;                         \
        else if (f_ == 1) pf0_.v[4 + r_] = (__bf16)p_;                         \
        else if (f_ == 2) pf1_.v[r_]     = (__bf16)p_;                         \
        else              pf1_.v[4 + r_] = (__bf16)p_;                         \
      }                                                                        \
    }                                                                          \
    l_run += lsum_;                                                            \
    _Pragma("unroll")                                                          \
    for (int n_ = 0; n_ < 4; ++n_) {                                           \
      B8 v0_, v1_;                                                             \
      uint2 a0_ = *(const uint2*)(vrd[0] + n_ * 1024);                         \
      uint2 a1_ = *(const uint2*)(vrd[1] + n_ * 1024);                         \
      uint2 a2_ = *(const uint2*)(vrd[2] + n_ * 1024);                         \
      uint2 a3_ = *(const uint2*)(vrd[3] + n_ * 1024);                         \
      v0_.u[0] = a0_.x; v0_.u[1] = a0_.y;                                      \
      v0_.u[2] = a1_.x; v0_.u[3] = a1_.y;                                      \
      v1_.u[0] = a2_.x; v1_.u[1] = a2_.y;                                      \
      v1_.u[2] = a3_.x; v1_.u[3] = a3_.y;                                      \
      acc[n_] = mfma_bf16(v0_.v, pf0_.v, acc[n_]);                             \
      acc[n_] = mfma_bf16(v1_.v, pf1_.v, acc[n_]);                             \
    }                                                                          \
  } while (0)

  // prologue: stage tile 0
  SLOAD(0);
  SWRITE();
  __syncthreads();

  for (int t = 0; t < ntile - 1; ++t) {
    SLOAD(t + 1);            // issue early: latency hides under FRAGX
    FRAGX(t << 6, 0);
    __syncthreads();         // all waves done reading LDS tile t
    SWRITE();
    __syncthreads();         // tile t+1 visible
  }
  FRAGX((ntile - 1) << 6, 1);  // peeled masked diagonal tile

  // epilogue: lane holds q = qcol; reduce per-lane l over g-groups
  float lt = l_run + __shfl_xor(l_run, 16);
  lt += __shfl_xor(lt, 32);
  const float ri = 1.0f / lt;
  unsigned short* ob = At + (bS + qcol) * Dm + hoff;
#pragma unroll
  for (int n = 0; n < 4; ++n) {
    B4 ov;
    ov.v[0] = (__bf16)(acc[n][0] * ri);
    ov.v[1] = (__bf16)(acc[n][1] * ri);
    ov.v[2] = (__bf16)(acc[n][2] * ri);
    ov.v[3] = (__bf16)(acc[n][3] * ri);
    *(uint2*)(ob + n * 16 + g * 4) = ov.u2;
  }
}

extern "C" void kernel_launch(void* const* d_in, const int* in_sizes, int n_in,
                              void* d_out, int out_size, void* d_ws, size_t ws_size,
                              hipStream_t stream) {
  const float* q    = (const float*)d_in[0];
  const float* k    = (const float*)d_in[1];
  const float* v    = (const float*)d_in[2];
  // d_in[3] = causal mask, analytically known -> unused
  const float* wq_w = (const float*)d_in[4];
  const float* wq_b = (const float*)d_in[5];
  const float* wk_w = (const float*)d_in[6];
  const float* wk_b = (const float*)d_in[7];
  const float* wv_w = (const float*)d_in[8];
  const float* wv_b = (const float*)d_in[9];
  const float* ow   = (const float*)d_in[10];
  const float* ob   = (const float*)d_in[11];
  float* out = (float*)d_out;

  char* ws = (char*)d_ws;
  unsigned short* Qp = (unsigned short*)(ws);                  // 8MB bf16 [4096,1024]
  unsigned short* Kp = (unsigned short*)(ws + (8u << 20));     // 8MB
  unsigned short* Vt = (unsigned short*)(ws + (16u << 20));    // 8MB [B,H,64,2048]
  unsigned short* At = (unsigned short*)(ws + (24u << 20));    // 8MB [4096,1024]

  dim3 blk(256);
  gemm_bt<0, false><<<256, blk, 0, stream>>>(q, wq_w, wq_b, Qp, 4096, 1024, 1024);
  gemm_bt<0, false><<<256, blk, 0, stream>>>(k, wk_w, wk_b, Kp, 4096, 1024, 1024);
  gemm_bt<1, false><<<256, blk, 0, stream>>>(v, wv_w, wv_b, Vt, 4096, 1024, 1024);
  flash_alibi<<<1024, blk, 0, stream>>>(Qp, Kp, Vt, At);
  gemm_bt<2, true><<<256, blk, 0, stream>>>(At, ow, ob, out, 4096, 1024, 1024);
}

// Round 6
// 178.616 us; speedup vs baseline: 2.6412x; 1.5006x over previous
//
#include <hip/hip_runtime.h>
#include <hip/hip_bf16.h>
#include <cstdint>
#include <cstddef>

#define DEV static __device__ __forceinline__

typedef float f32x4 __attribute__((ext_vector_type(4)));
typedef __bf16 bf16x8 __attribute__((ext_vector_type(8)));
typedef __bf16 bf16x4 __attribute__((ext_vector_type(4)));

#define EXP2F(x) __builtin_amdgcn_exp2f(x)

union B8 {
  uint4 u4;
  uint32_t u[4];
  unsigned short s[8];
  bf16x8 v;
};
union B4 {
  uint2 u2;
  unsigned short s[4];
  bf16x4 v;
};

DEV unsigned short bfbits(float x) {
  union { __bf16 h; unsigned short s; } z; z.h = (__bf16)x; return z.s;
}
DEV uint32_t pk2(float x, float y) {
  union { __bf16 h[2]; uint32_t u; } z;
  z.h[0] = (__bf16)x; z.h[1] = (__bf16)y; return z.u;
}

DEV f32x4 mfma_bf16(bf16x8 a, bf16x8 b, f32x4 c) {
  return __builtin_amdgcn_mfma_f32_16x16x32_bf16(a, b, c, 0, 0, 0);
}

// ---------------------------------------------------------------------------
// Fused QKV projection GEMM. Grid 768 = 3 proj x 256 tiles (128x128).
// XCD-bijective swizzle: lbid = (bid&7)*96 + bid>>3 -> each XCD owns a
// contiguous run of tiles (A-panel reused by its 8 nb-neighbors in one L2;
// whole B fits L2). proj: 0=q->Qp (mode0), 1=k->Kp (mode0), 2=v->Vt (mode1).
// A fp32 [4096,1024]; B fp32 [1024,1024] (nn.Linear weight, used as B^T);
// 256 thr / 4 waves (2x2), BK=64, 16x16x32 bf16 MFMA, XOR-swizzled LDS.
// ---------------------------------------------------------------------------
__global__ __launch_bounds__(256, 2)
void gemm_qkv(const float* __restrict__ q, const float* __restrict__ k,
              const float* __restrict__ v,
              const float* __restrict__ wq, const float* __restrict__ wk,
              const float* __restrict__ wv,
              const float* __restrict__ bq, const float* __restrict__ bk,
              const float* __restrict__ bv,
              unsigned short* __restrict__ Qp, unsigned short* __restrict__ Kp,
              unsigned short* __restrict__ Vt) {
  const int K = 1024, N = 1024;
  __shared__ __align__(16) unsigned short As[128 * 64];
  __shared__ __align__(16) unsigned short Bs[128 * 64];
  const int bid = blockIdx.x;
  const int lbid = (bid & 7) * 96 + (bid >> 3);    // bijective, 768 = 8*96
  const int proj = lbid >> 8;                       // 0..2
  const int t = lbid & 255;
  const int mb = t >> 3, nb = t & 7;
  const float* A   = proj == 0 ? q  : proj == 1 ? k  : v;
  const float* Bw  = proj == 0 ? wq : proj == 1 ? wk : wv;
  const float* bias= proj == 0 ? bq : proj == 1 ? bk : bv;
  const int tid = threadIdx.x;
  const int lane = tid & 63, w = tid >> 6;
  const int wm = w >> 1, wn = w & 1;
  f32x4 acc[4][4] = {};

  for (int kt = 0; kt < 16; ++kt) {
    __syncthreads();
#pragma unroll
    for (int i = 0; i < 4; ++i) {
      const int chunk = tid + (i << 8);      // 0..1023 : 128 rows x 8 slots
      const int r = chunk >> 3, c8 = chunk & 7;
      const int slot = c8 ^ (r & 7);
      const float* srcA = A + (size_t)(mb * 128 + r) * K + (kt << 6) + (c8 << 3);
      float4 a0 = *(const float4*)srcA;
      float4 a1 = *(const float4*)(srcA + 4);
      B8 pa;
      pa.u[0] = pk2(a0.x, a0.y); pa.u[1] = pk2(a0.z, a0.w);
      pa.u[2] = pk2(a1.x, a1.y); pa.u[3] = pk2(a1.z, a1.w);
      *(uint4*)&As[(r << 6) + (slot << 3)] = pa.u4;

      const float* srcB = Bw + (size_t)(nb * 128 + r) * K + (kt << 6) + (c8 << 3);
      float4 b0 = *(const float4*)srcB;
      float4 b1 = *(const float4*)(srcB + 4);
      B8 pb;
      pb.u[0] = pk2(b0.x, b0.y); pb.u[1] = pk2(b0.z, b0.w);
      pb.u[2] = pk2(b1.x, b1.y); pb.u[3] = pk2(b1.z, b1.w);
      *(uint4*)&Bs[(r << 6) + (slot << 3)] = pb.u4;
    }
    __syncthreads();

    B8 af[4][2], bfr[4][2];
#pragma unroll
    for (int mi = 0; mi < 4; ++mi)
#pragma unroll
      for (int kk = 0; kk < 2; ++kk) {
        const int row = wm * 64 + mi * 16 + (lane & 15);
        const int slot = ((kk << 2) + (lane >> 4)) ^ (row & 7);
        af[mi][kk].u4 = *(const uint4*)&As[(row << 6) + (slot << 3)];
      }
#pragma unroll
    for (int ni = 0; ni < 4; ++ni)
#pragma unroll
      for (int kk = 0; kk < 2; ++kk) {
        const int row = wn * 64 + ni * 16 + (lane & 15);
        const int slot = ((kk << 2) + (lane >> 4)) ^ (row & 7);
        bfr[ni][kk].u4 = *(const uint4*)&Bs[(row << 6) + (slot << 3)];
      }
#pragma unroll
    for (int kk = 0; kk < 2; ++kk)
#pragma unroll
      for (int mi = 0; mi < 4; ++mi)
#pragma unroll
        for (int ni = 0; ni < 4; ++ni)
          acc[mi][ni] = mfma_bf16(af[mi][kk].v, bfr[ni][kk].v, acc[mi][ni]);
  }

  unsigned short* Cv = proj == 0 ? Qp : proj == 1 ? Kp : Vt;
  const bool vt_mode = (proj == 2);
#pragma unroll
  for (int ni = 0; ni < 4; ++ni) {
    const int col = nb * 128 + wn * 64 + ni * 16 + (lane & 15);
    const float bv = bias[col];
#pragma unroll
    for (int mi = 0; mi < 4; ++mi) {
#pragma unroll
      for (int r = 0; r < 4; ++r) {
        const int row = mb * 128 + wm * 64 + mi * 16 + (lane >> 4) * 4 + r;
        const float val = acc[mi][ni][r] + bv;
        if (!vt_mode) {
          Cv[(size_t)row * N + col] = bfbits(val);
        } else {
          const int b = row >> 11, ss = row & 2047, hh = col >> 6, d = col & 63;
          Cv[((size_t)((b * 16 + hh) * 64 + d) << 11) + ss] = bfbits(val);
        }
      }
    }
  }
}

// ---------------------------------------------------------------------------
// Output projection: out = At[4096,1024](bf16) @ ow[1024,1024]^T + ob, fp32.
// BM=64, BN=128, BK=64 -> grid 512 (2 blocks/CU). 4 waves 1x4 (wave: 64x32,
// acc[4][2]). LDS 24KB. Same XOR swizzle; A staged as pure 16B copies.
// ---------------------------------------------------------------------------
__global__ __launch_bounds__(256, 2)
void gemm_out(const unsigned short* __restrict__ At, const float* __restrict__ Bw,
              const float* __restrict__ bias, float* __restrict__ Cv) {
  const int K = 1024, N = 1024;
  __shared__ __align__(16) unsigned short As[64 * 64];
  __shared__ __align__(16) unsigned short Bs[128 * 64];
  const int bid = blockIdx.x;
  const int lbid = (bid & 7) * 64 + (bid >> 3);    // bijective, 512 = 8*64
  const int mb = lbid >> 3, nb = lbid & 7;
  const int tid = threadIdx.x;
  const int lane = tid & 63, w = tid >> 6;
  const int qc = lane & 15, g = lane >> 4;
  f32x4 acc[4][2] = {};

  for (int kt = 0; kt < 16; ++kt) {
    __syncthreads();
#pragma unroll
    for (int i = 0; i < 6; ++i) {
      const int chunk = tid + (i << 8);
      if (i < 2) {                         // A: chunks 0..511 (64 rows x 8)
        const int r = chunk >> 3, c8 = chunk & 7;
        const int slot = c8 ^ (r & 7);
        uint4 pa = *(const uint4*)(At + (size_t)(mb * 64 + r) * K + (kt << 6) + (c8 << 3));
        *(uint4*)&As[(r << 6) + (slot << 3)] = pa;
      } else {                             // B: chunks 0..1023 (128 rows x 8)
        const int cb = chunk - 512;
        const int r = cb >> 3, c8 = cb & 7;
        const int slot = c8 ^ (r & 7);
        const float* srcB = Bw + (size_t)(nb * 128 + r) * K + (kt << 6) + (c8 << 3);
        float4 b0 = *(const float4*)srcB;
        float4 b1 = *(const float4*)(srcB + 4);
        B8 pb;
        pb.u[0] = pk2(b0.x, b0.y); pb.u[1] = pk2(b0.z, b0.w);
        pb.u[2] = pk2(b1.x, b1.y); pb.u[3] = pk2(b1.z, b1.w);
        *(uint4*)&Bs[(r << 6) + (slot << 3)] = pb.u4;
      }
    }
    __syncthreads();

    B8 af[4][2], bfr[2][2];
#pragma unroll
    for (int mi = 0; mi < 4; ++mi)
#pragma unroll
      for (int kk = 0; kk < 2; ++kk) {
        const int row = mi * 16 + qc;
        const int slot = ((kk << 2) + g) ^ (row & 7);
        af[mi][kk].u4 = *(const uint4*)&As[(row << 6) + (slot << 3)];
      }
#pragma unroll
    for (int ni = 0; ni < 2; ++ni)
#pragma unroll
      for (int kk = 0; kk < 2; ++kk) {
        const int row = w * 32 + ni * 16 + qc;
        const int slot = ((kk << 2) + g) ^ (row & 7);
        bfr[ni][kk].u4 = *(const uint4*)&Bs[(row << 6) + (slot << 3)];
      }
#pragma unroll
    for (int kk = 0; kk < 2; ++kk)
#pragma unroll
      for (int mi = 0; mi < 4; ++mi)
#pragma unroll
        for (int ni = 0; ni < 2; ++ni)
          acc[mi][ni] = mfma_bf16(af[mi][kk].v, bfr[ni][kk].v, acc[mi][ni]);
  }

#pragma unroll
  for (int ni = 0; ni < 2; ++ni) {
    const int col = nb * 128 + w * 32 + ni * 16 + qc;
    const float bv = bias[col];
#pragma unroll
    for (int mi = 0; mi < 4; ++mi) {
#pragma unroll
      for (int r = 0; r < 4; ++r) {
        const int row = mb * 64 + mi * 16 + g * 4 + r;
        Cv[(size_t)row * N + col] = acc[mi][ni][r] + bv;
      }
    }
  }
}

// ---------------------------------------------------------------------------
// Causal flash attention + ALiBi (unchanged from r5, passing).
// ---------------------------------------------------------------------------
__global__ __launch_bounds__(256, 4)
void flash_alibi(const unsigned short* __restrict__ Qp,
                 const unsigned short* __restrict__ Kp,
                 const unsigned short* __restrict__ Vt,
                 unsigned short* __restrict__ At) {
  const int S = 2048, Dm = 1024;
  const int bid = blockIdx.x;
  const int z = bid >> 5, y = bid & 31;
  const int s = (y + z) & 31;
  const int h = z & 15, b = z >> 4;
  const int tid = threadIdx.x, lane = tid & 63, w = tid >> 6;
  const int qc = lane & 15, g = lane >> 4;
  const int q0 = s * 64 + w * 16;
  const int qcol = q0 + qc;
  const float slope = exp2f(-(float)(h + 1));   // H=16 power-of-2 slopes
  const float L2E = 1.44269504f;
  const float ls1 = L2E * slope;
  const float THR = 11.54f;                      // 8 * log2(e)
  const size_t bS = (size_t)b * S;
  const int hoff = h * 64;
  const int ntile = s + 1;

  __shared__ __align__(16) unsigned short Ks[64 * 64];   // 8KB [kv][hd swz]
  __shared__ __align__(16) unsigned short Vs[64 * 64];   // 8KB [d][s swz]

  B8 qf[2];
  {
    const unsigned short* qa = Qp + (bS + qcol) * Dm + hoff + g * 8;
    qf[0].u4 = *(const uint4*)qa; qf[1].u4 = *(const uint4*)(qa + 32);
  }

  const int srow = tid >> 2;                 // 0..63
  const int sg0 = (tid & 3) * 2;             // granule (16B unit) 0..6 even
  const int ssw = srow & 7;
  const unsigned short* kg0 = Kp + (bS + srow) * Dm + hoff + sg0 * 8;
  const unsigned short* vg0 = Vt + (((size_t)((b * 16 + h) * 64 + srow)) << 11) + sg0 * 8;
  unsigned short* kw0 = &Ks[srow * 64 + ((sg0 ^ ssw) << 3)];
  unsigned short* kw1 = &Ks[srow * 64 + (((sg0 + 1) ^ ssw) << 3)];
  unsigned short* vw0 = &Vs[srow * 64 + ((sg0 ^ ssw) << 3)];
  unsigned short* vw1 = &Vs[srow * 64 + (((sg0 + 1) ^ ssw) << 3)];
  uint4 krA, krB, vrA, vrB;

#define SLOAD(TT) do {                                                         \
    const unsigned short* kp_ = kg0 + (((size_t)(TT)) << 6) * Dm;              \
    krA = *(const uint4*)kp_; krB = *(const uint4*)(kp_ + 8);                  \
    const unsigned short* vp_ = vg0 + ((TT) << 6);                             \
    vrA = *(const uint4*)vp_; vrB = *(const uint4*)(vp_ + 8);                  \
  } while (0)
#define SWRITE() do {                                                          \
    *(uint4*)kw0 = krA; *(uint4*)kw1 = krB;                                    \
    *(uint4*)vw0 = vrA; *(uint4*)vw1 = vrB;                                    \
  } while (0)

  const int sw = qc & 7;
  const unsigned short* krd0 = &Ks[qc * 64 + ((g ^ sw) << 3)];          // +f*1024
  const unsigned short* krd1 = &Ks[qc * 64 + (((g ^ sw) ^ 4) << 3)];
  const unsigned short* vrd[4];
#pragma unroll
  for (int j = 0; j < 4; ++j)
    vrd[j] = &Vs[qc * 64 + ((((2 * j) + (g >> 1)) ^ sw) << 3) + (g & 1) * 4];  // +n*1024

  f32x4 acc[4] = {};
  float m_run = 0.f, l_run = 0.f;
  const float abq = slope * (float)(g * 4 - qcol);

#define FRAGX(KV0, MASKED) do {                                                \
    const float kv0f = (float)(KV0);                                           \
    f32x4 sc_[4] = {};                                                         \
    _Pragma("unroll")                                                          \
    for (int f_ = 0; f_ < 4; ++f_) {                                           \
      B8 k0_, k1_;                                                             \
      k0_.u4 = *(const uint4*)(krd0 + f_ * 1024);                              \
      k1_.u4 = *(const uint4*)(krd1 + f_ * 1024);                              \
      sc_[f_] = mfma_bf16(k0_.v, qf[0].v, sc_[f_]);                            \
      sc_[f_] = mfma_bf16(k1_.v, qf[1].v, sc_[f_]);                            \
    }                                                                          \
    const float cb_ = (fmaf(slope, kv0f, abq) - m_run) * L2E;                  \
    float ein_[4][4]; float emax_ = -1e30f;                                    \
    _Pragma("unroll")                                                          \
    for (int f_ = 0; f_ < 4; ++f_) {                                           \
      const float cf_ = cb_ + (float)(16 * f_) * ls1;                          \
      _Pragma("unroll")                                                        \
      for (int r_ = 0; r_ < 4; ++r_) {                                         \
        float e_ = fmaf(sc_[f_][r_], L2E, cf_ + (float)r_ * ls1);              \
        if (MASKED) {                                                          \
          const int kv_ = (KV0) + f_ * 16 + g * 4 + r_;                        \
          if (kv_ > qcol) e_ = -1e30f;                                         \
        }                                                                      \
        ein_[f_][r_] = e_; emax_ = fmaxf(emax_, e_);                           \
      }                                                                        \
    }                                                                          \
    if (!__all(emax_ <= THR)) {                                                \
      float er_ = fmaxf(emax_, __shfl_xor(emax_, 16));                         \
      er_ = fmaxf(er_, __shfl_xor(er_, 32));                                   \
      er_ = fmaxf(er_, 0.f);                                                   \
      m_run += er_ * 0.69314718f;                                              \
      const float sfac_ = EXP2F(-er_);                                         \
      l_run *= sfac_;                                                          \
      _Pragma("unroll") for (int n_ = 0; n_ < 4; ++n_) acc[n_] = acc[n_] * sfac_; \
      _Pragma("unroll") for (int f_ = 0; f_ < 4; ++f_)                         \
        _Pragma("unroll") for (int r_ = 0; r_ < 4; ++r_) ein_[f_][r_] -= er_;  \
    }                                                                          \
    B8 pf0_, pf1_; float lsum_ = 0.f;                                          \
    _Pragma("unroll")                                                          \
    for (int f_ = 0; f_ < 4; ++f_) {                                           \
      _Pragma("unroll")                                                        \
      for (int r_ = 0; r_ < 4; ++r_) {                                         \
        const float p_ = EXP2F(ein_[f_][r_]);                                  \
        lsum_ += p_;                                                           \
        if (f_ == 0)      pf0_.v[r_]     = (__bf16)p_;                         \
        else if (f_ == 1) pf0_.v[4 + r_] = (__bf16)p_;                         \
        else if (f_ == 2) pf1_.v[r_]     = (__bf16)p_;                         \
        else              pf1_.v[4 + r_] = (__bf16)p_;                         \
      }                                                                        \
    }                                                                          \
    l_run += lsum_;                                                            \
    _Pragma("unroll")                                                          \
    for (int n_ = 0; n_ < 4; ++n_) {                                           \
      B8 v0_, v1_;                                                             \
      uint2 a0_ = *(const uint2*)(vrd[0] + n_ * 1024);                         \
      uint2 a1_ = *(const uint2*)(vrd[1] + n_ * 1024);                         \
      uint2 a2_ = *(const uint2*)(vrd[2] + n_ * 1024);                         \
      uint2 a3_ = *(const uint2*)(vrd[3] + n_ * 1024);                         \
      v0_.u[0] = a0_.x; v0_.u[1] = a0_.y;                                      \
      v0_.u[2] = a1_.x; v0_.u[3] = a1_.y;                                      \
      v1_.u[0] = a2_.x; v1_.u[1] = a2_.y;                                      \
      v1_.u[2] = a3_.x; v1_.u[3] = a3_.y;                                      \
      acc[n_] = mfma_bf16(v0_.v, pf0_.v, acc[n_]);                             \
      acc[n_] = mfma_bf16(v1_.v, pf1_.v, acc[n_]);                             \
    }                                                                          \
  } while (0)

  SLOAD(0);
  SWRITE();
  __syncthreads();

  for (int t = 0; t < ntile - 1; ++t) {
    SLOAD(t + 1);            // issue early: latency hides under FRAGX
    FRAGX(t << 6, 0);
    __syncthreads();         // all waves done reading LDS tile t
    SWRITE();
    __syncthreads();         // tile t+1 visible
  }
  FRAGX((ntile - 1) << 6, 1);  // peeled masked diagonal tile

  float lt = l_run + __shfl_xor(l_run, 16);
  lt += __shfl_xor(lt, 32);
  const float ri = 1.0f / lt;
  unsigned short* ob = At + (bS + qcol) * Dm + hoff;
#pragma unroll
  for (int n = 0; n < 4; ++n) {
    B4 ov;
    ov.v[0] = (__bf16)(acc[n][0] * ri);
    ov.v[1] = (__bf16)(acc[n][1] * ri);
    ov.v[2] = (__bf16)(acc[n][2] * ri);
    ov.v[3] = (__bf16)(acc[n][3] * ri);
    *(uint2*)(ob + n * 16 + g * 4) = ov.u2;
  }
}

extern "C" void kernel_launch(void* const* d_in, const int* in_sizes, int n_in,
                              void* d_out, int out_size, void* d_ws, size_t ws_size,
                              hipStream_t stream) {
  const float* q    = (const float*)d_in[0];
  const float* k    = (const float*)d_in[1];
  const float* v    = (const float*)d_in[2];
  // d_in[3] = causal mask, analytically known -> unused
  const float* wq_w = (const float*)d_in[4];
  const float* wq_b = (const float*)d_in[5];
  const float* wk_w = (const float*)d_in[6];
  const float* wk_b = (const float*)d_in[7];
  const float* wv_w = (const float*)d_in[8];
  const float* wv_b = (const float*)d_in[9];
  const float* ow   = (const float*)d_in[10];
  const float* ob   = (const float*)d_in[11];
  float* out = (float*)d_out;

  char* ws = (char*)d_ws;
  unsigned short* Qp = (unsigned short*)(ws);                  // 8MB bf16 [4096,1024]
  unsigned short* Kp = (unsigned short*)(ws + (8u << 20));     // 8MB
  unsigned short* Vt = (unsigned short*)(ws + (16u << 20));    // 8MB [B,H,64,2048]
  unsigned short* At = (unsigned short*)(ws + (24u << 20));    // 8MB [4096,1024]

  dim3 blk(256);
  gemm_qkv<<<768, blk, 0, stream>>>(q, k, v, wq_w, wk_w, wv_w,
                                    wq_b, wk_b, wv_b, Qp, Kp, Vt);
  flash_alibi<<<1024, blk, 0, stream>>>(Qp, Kp, Vt, At);
  gemm_out<<<512, blk, 0, stream>>>(At, ow, ob, out);
}

// Round 7
// 121.019 us; speedup vs baseline: 3.8983x; 1.4759x over previous
//
#include <hip/hip_runtime.h>
#include <hip/hip_bf16.h>
#include <cstdint>
#include <cstddef>

#define DEV static __device__ __forceinline__

typedef float f32x4 __attribute__((ext_vector_type(4)));
typedef __bf16 bf16x8 __attribute__((ext_vector_type(8)));
typedef __bf16 bf16x4 __attribute__((ext_vector_type(4)));

#define EXP2F(x) __builtin_amdgcn_exp2f(x)

union B8 {
  uint4 u4;
  uint32_t u[4];
  unsigned short s[8];
  bf16x8 v;
};
union B4 {
  uint2 u2;
  unsigned short s[4];
  bf16x4 v;
};

DEV unsigned short bfbits(float x) {
  union { __bf16 h; unsigned short s; } z; z.h = (__bf16)x; return z.s;
}
DEV uint32_t pk2(float x, float y) {
  union { __bf16 h[2]; uint32_t u; } z;
  z.h[0] = (__bf16)x; z.h[1] = (__bf16)y; return z.u;
}

DEV f32x4 mfma_bf16(bf16x8 a, bf16x8 b, f32x4 c) {
  return __builtin_amdgcn_mfma_f32_16x16x32_bf16(a, b, c, 0, 0, 0);
}

// async global->LDS, 16B per lane; LDS dest = wave-uniform base + lane*16
DEV void gload16(const void* g, void* l) {
  __builtin_amdgcn_global_load_lds(
      (const __attribute__((address_space(1))) void*)g,
      (__attribute__((address_space(3))) void*)l, 16, 0, 0);
}

// ===========================================================================
// cvt_all: fp32 -> bf16 for q,k,v (2^22 elems each) + wq,wk,wv,ow (2^20 each)
// into one contiguous 2^24-elem bf16 region. Grid 8192 x 256; thread: 8 elems.
// ===========================================================================
__global__ __launch_bounds__(256)
void cvt_all(const float* __restrict__ q, const float* __restrict__ k,
             const float* __restrict__ v,
             const float* __restrict__ wq, const float* __restrict__ wk,
             const float* __restrict__ wv, const float* __restrict__ ow,
             unsigned short* __restrict__ dst) {
  const int bid = blockIdx.x;
  const size_t base = ((size_t)bid << 11) + ((size_t)threadIdx.x << 3);
  const float* src;
  size_t rel;
  if (bid < 2048)      { src = q; rel = base; }
  else if (bid < 4096) { src = k; rel = base - (1u << 22); }
  else if (bid < 6144) { src = v; rel = base - (2u << 22); }
  else {
    const int wseg = (bid - 6144) >> 9;
    src = wseg == 0 ? wq : wseg == 1 ? wk : wseg == 2 ? wv : ow;
    rel = base & 1048575u;
  }
  float4 a0 = *(const float4*)(src + rel);
  float4 a1 = *(const float4*)(src + rel + 4);
  B8 p;
  p.u[0] = pk2(a0.x, a0.y); p.u[1] = pk2(a0.z, a0.w);
  p.u[2] = pk2(a1.x, a1.y); p.u[3] = pk2(a1.z, a1.w);
  *(uint4*)(dst + base) = p.u4;
}

// ===========================================================================
// Fused QKV GEMM, bf16 x bf16, global_load_lds staging (m97 structure).
// Grid 768 = 3 proj x (32 mb x 8 nb), XCD-bijective swizzle.
// LDS linear [128][64]; global source granule pre-swizzled (gran ^= row&7),
// ds_read uses the same XOR -> conflict-free both ways (rule #21).
// ===========================================================================
__global__ __launch_bounds__(256, 2)
void gemm_qkv_b(const unsigned short* __restrict__ qb,
                const unsigned short* __restrict__ kb,
                const unsigned short* __restrict__ vb,
                const unsigned short* __restrict__ wqb,
                const unsigned short* __restrict__ wkb,
                const unsigned short* __restrict__ wvb,
                const float* __restrict__ bq, const float* __restrict__ bk,
                const float* __restrict__ bv,
                unsigned short* __restrict__ Qp, unsigned short* __restrict__ Kp,
                unsigned short* __restrict__ Vt) {
  const int K = 1024, N = 1024;
  __shared__ __align__(16) unsigned short As[128 * 64];
  __shared__ __align__(16) unsigned short Bs[128 * 64];
  const int bid = blockIdx.x;
  const int lbid = (bid & 7) * 96 + (bid >> 3);    // bijective, 768 = 8*96
  const int proj = lbid >> 8;
  const int t = lbid & 255;
  const int mb = t >> 3, nb = t & 7;
  const unsigned short* A  = proj == 0 ? qb  : proj == 1 ? kb  : vb;
  const unsigned short* Bw = proj == 0 ? wqb : proj == 1 ? wkb : wvb;
  const float* bias        = proj == 0 ? bq  : proj == 1 ? bk  : bv;
  const int tid = threadIdx.x;
  const int lane = tid & 63, w = tid >> 6;
  const int wm = w >> 1, wn = w & 1;
  f32x4 acc[4][4] = {};

  // staging: wave w covers rows 32w..32w+31 (4 issues x 8 rows) of A and B
  const int lrow = lane >> 3;               // 0..7
  const int lg = lane & 7;
  const int gsrc = lg ^ lrow;               // pre-swizzled source granule
  const unsigned short* ag = A  + (size_t)(mb * 128 + w * 32 + lrow) * K + gsrc * 8;
  const unsigned short* bg = Bw + (size_t)(nb * 128 + w * 32 + lrow) * K + gsrc * 8;
  unsigned short* al = &As[(w * 32) * 64];
  unsigned short* bl = &Bs[(w * 32) * 64];

  for (int kt = 0; kt < 16; ++kt) {
    __syncthreads();
#pragma unroll
    for (int i = 0; i < 4; ++i) {
      gload16(ag + i * (8 * 1024) + kt * 64, al + (i * 8) * 64);
      gload16(bg + i * (8 * 1024) + kt * 64, bl + (i * 8) * 64);
    }
    __syncthreads();   // vmcnt drain -> tile visible

    B8 af[4][2], bfr[4][2];
#pragma unroll
    for (int mi = 0; mi < 4; ++mi)
#pragma unroll
      for (int kk = 0; kk < 2; ++kk) {
        const int row = wm * 64 + mi * 16 + (lane & 15);
        const int slot = ((kk << 2) + (lane >> 4)) ^ (row & 7);
        af[mi][kk].u4 = *(const uint4*)&As[(row << 6) + (slot << 3)];
      }
#pragma unroll
    for (int ni = 0; ni < 4; ++ni)
#pragma unroll
      for (int kk = 0; kk < 2; ++kk) {
        const int row = wn * 64 + ni * 16 + (lane & 15);
        const int slot = ((kk << 2) + (lane >> 4)) ^ (row & 7);
        bfr[ni][kk].u4 = *(const uint4*)&Bs[(row << 6) + (slot << 3)];
      }
#pragma unroll
    for (int kk = 0; kk < 2; ++kk)
#pragma unroll
      for (int mi = 0; mi < 4; ++mi)
#pragma unroll
        for (int ni = 0; ni < 4; ++ni)
          acc[mi][ni] = mfma_bf16(af[mi][kk].v, bfr[ni][kk].v, acc[mi][ni]);
  }

  unsigned short* Cv = proj == 0 ? Qp : proj == 1 ? Kp : Vt;
  const bool vt_mode = (proj == 2);
#pragma unroll
  for (int ni = 0; ni < 4; ++ni) {
    const int col = nb * 128 + wn * 64 + ni * 16 + (lane & 15);
    const float bv = bias[col];
#pragma unroll
    for (int mi = 0; mi < 4; ++mi) {
#pragma unroll
      for (int r = 0; r < 4; ++r) {
        const int row = mb * 128 + wm * 64 + mi * 16 + (lane >> 4) * 4 + r;
        const float val = acc[mi][ni][r] + bv;
        if (!vt_mode) {
          Cv[(size_t)row * N + col] = bfbits(val);
        } else {
          const int b = row >> 11, ss = row & 2047, hh = col >> 6, d = col & 63;
          Cv[((size_t)((b * 16 + hh) * 64 + d) << 11) + ss] = bfbits(val);
        }
      }
    }
  }
}

// ===========================================================================
// Output projection, bf16 x bf16 -> fp32, global_load_lds staging.
// BM=64, BN=128, BK=64; grid 512 (2 blocks/CU). Waves 1x4 (64 x 32 each).
// ===========================================================================
__global__ __launch_bounds__(256, 2)
void gemm_out_b(const unsigned short* __restrict__ At,
                const unsigned short* __restrict__ wob,
                const float* __restrict__ bias, float* __restrict__ Cv) {
  const int K = 1024, N = 1024;
  __shared__ __align__(16) unsigned short As[64 * 64];
  __shared__ __align__(16) unsigned short Bs[128 * 64];
  const int bid = blockIdx.x;
  const int lbid = (bid & 7) * 64 + (bid >> 3);    // bijective, 512 = 8*64
  const int mb = lbid >> 3, nb = lbid & 7;
  const int tid = threadIdx.x;
  const int lane = tid & 63, w = tid >> 6;
  const int qc = lane & 15, g = lane >> 4;
  f32x4 acc[4][2] = {};

  const int lrow = lane >> 3, lg = lane & 7;
  const int gsrc = lg ^ lrow;
  const unsigned short* ag = At  + (size_t)(mb * 64 + w * 16 + lrow) * K + gsrc * 8;
  const unsigned short* bg = wob + (size_t)(nb * 128 + w * 32 + lrow) * K + gsrc * 8;
  unsigned short* al = &As[(w * 16) * 64];
  unsigned short* bl = &Bs[(w * 32) * 64];

  for (int kt = 0; kt < 16; ++kt) {
    __syncthreads();
#pragma unroll
    for (int i = 0; i < 2; ++i)
      gload16(ag + i * (8 * 1024) + kt * 64, al + (i * 8) * 64);
#pragma unroll
    for (int i = 0; i < 4; ++i)
      gload16(bg + i * (8 * 1024) + kt * 64, bl + (i * 8) * 64);
    __syncthreads();

    B8 af[4][2], bfr[2][2];
#pragma unroll
    for (int mi = 0; mi < 4; ++mi)
#pragma unroll
      for (int kk = 0; kk < 2; ++kk) {
        const int row = mi * 16 + qc;
        const int slot = ((kk << 2) + g) ^ (row & 7);
        af[mi][kk].u4 = *(const uint4*)&As[(row << 6) + (slot << 3)];
      }
#pragma unroll
    for (int ni = 0; ni < 2; ++ni)
#pragma unroll
      for (int kk = 0; kk < 2; ++kk) {
        const int row = w * 32 + ni * 16 + qc;
        const int slot = ((kk << 2) + g) ^ (row & 7);
        bfr[ni][kk].u4 = *(const uint4*)&Bs[(row << 6) + (slot << 3)];
      }
#pragma unroll
    for (int kk = 0; kk < 2; ++kk)
#pragma unroll
      for (int mi = 0; mi < 4; ++mi)
#pragma unroll
        for (int ni = 0; ni < 2; ++ni)
          acc[mi][ni] = mfma_bf16(af[mi][kk].v, bfr[ni][kk].v, acc[mi][ni]);
  }

#pragma unroll
  for (int ni = 0; ni < 2; ++ni) {
    const int col = nb * 128 + w * 32 + ni * 16 + qc;
    const float bv = bias[col];
#pragma unroll
    for (int mi = 0; mi < 4; ++mi) {
#pragma unroll
      for (int r = 0; r < 4; ++r) {
        const int row = mb * 64 + mi * 16 + g * 4 + r;
        Cv[(size_t)row * N + col] = acc[mi][ni][r] + bv;
      }
    }
  }
}

// ===========================================================================
// FALLBACK PATH (r6, used only if ws_size < 64MB): fp32 reg-staged GEMMs.
// ===========================================================================
__global__ __launch_bounds__(256, 2)
void gemm_qkv(const float* __restrict__ q, const float* __restrict__ k,
              const float* __restrict__ v,
              const float* __restrict__ wq, const float* __restrict__ wk,
              const float* __restrict__ wv,
              const float* __restrict__ bq, const float* __restrict__ bk,
              const float* __restrict__ bv,
              unsigned short* __restrict__ Qp, unsigned short* __restrict__ Kp,
              unsigned short* __restrict__ Vt) {
  const int K = 1024, N = 1024;
  __shared__ __align__(16) unsigned short As[128 * 64];
  __shared__ __align__(16) unsigned short Bs[128 * 64];
  const int bid = blockIdx.x;
  const int lbid = (bid & 7) * 96 + (bid >> 3);
  const int proj = lbid >> 8;
  const int t = lbid & 255;
  const int mb = t >> 3, nb = t & 7;
  const float* A   = proj == 0 ? q  : proj == 1 ? k  : v;
  const float* Bw  = proj == 0 ? wq : proj == 1 ? wk : wv;
  const float* bias= proj == 0 ? bq : proj == 1 ? bk : bv;
  const int tid = threadIdx.x;
  const int lane = tid & 63, w = tid >> 6;
  const int wm = w >> 1, wn = w & 1;
  f32x4 acc[4][4] = {};

  for (int kt = 0; kt < 16; ++kt) {
    __syncthreads();
#pragma unroll
    for (int i = 0; i < 4; ++i) {
      const int chunk = tid + (i << 8);
      const int r = chunk >> 3, c8 = chunk & 7;
      const int slot = c8 ^ (r & 7);
      const float* srcA = A + (size_t)(mb * 128 + r) * K + (kt << 6) + (c8 << 3);
      float4 a0 = *(const float4*)srcA;
      float4 a1 = *(const float4*)(srcA + 4);
      B8 pa;
      pa.u[0] = pk2(a0.x, a0.y); pa.u[1] = pk2(a0.z, a0.w);
      pa.u[2] = pk2(a1.x, a1.y); pa.u[3] = pk2(a1.z, a1.w);
      *(uint4*)&As[(r << 6) + (slot << 3)] = pa.u4;
      const float* srcB = Bw + (size_t)(nb * 128 + r) * K + (kt << 6) + (c8 << 3);
      float4 b0 = *(const float4*)srcB;
      float4 b1 = *(const float4*)(srcB + 4);
      B8 pb;
      pb.u[0] = pk2(b0.x, b0.y); pb.u[1] = pk2(b0.z, b0.w);
      pb.u[2] = pk2(b1.x, b1.y); pb.u[3] = pk2(b1.z, b1.w);
      *(uint4*)&Bs[(r << 6) + (slot << 3)] = pb.u4;
    }
    __syncthreads();

    B8 af[4][2], bfr[4][2];
#pragma unroll
    for (int mi = 0; mi < 4; ++mi)
#pragma unroll
      for (int kk = 0; kk < 2; ++kk) {
        const int row = wm * 64 + mi * 16 + (lane & 15);
        const int slot = ((kk << 2) + (lane >> 4)) ^ (row & 7);
        af[mi][kk].u4 = *(const uint4*)&As[(row << 6) + (slot << 3)];
      }
#pragma unroll
    for (int ni = 0; ni < 4; ++ni)
#pragma unroll
      for (int kk = 0; kk < 2; ++kk) {
        const int row = wn * 64 + ni * 16 + (lane & 15);
        const int slot = ((kk << 2) + (lane >> 4)) ^ (row & 7);
        bfr[ni][kk].u4 = *(const uint4*)&Bs[(row << 6) + (slot << 3)];
      }
#pragma unroll
    for (int kk = 0; kk < 2; ++kk)
#pragma unroll
      for (int mi = 0; mi < 4; ++mi)
#pragma unroll
        for (int ni = 0; ni < 4; ++ni)
          acc[mi][ni] = mfma_bf16(af[mi][kk].v, bfr[ni][kk].v, acc[mi][ni]);
  }

  unsigned short* Cv = proj == 0 ? Qp : proj == 1 ? Kp : Vt;
  const bool vt_mode = (proj == 2);
#pragma unroll
  for (int ni = 0; ni < 4; ++ni) {
    const int col = nb * 128 + wn * 64 + ni * 16 + (lane & 15);
    const float bv = bias[col];
#pragma unroll
    for (int mi = 0; mi < 4; ++mi) {
#pragma unroll
      for (int r = 0; r < 4; ++r) {
        const int row = mb * 128 + wm * 64 + mi * 16 + (lane >> 4) * 4 + r;
        const float val = acc[mi][ni][r] + bv;
        if (!vt_mode) {
          Cv[(size_t)row * N + col] = bfbits(val);
        } else {
          const int b = row >> 11, ss = row & 2047, hh = col >> 6, d = col & 63;
          Cv[((size_t)((b * 16 + hh) * 64 + d) << 11) + ss] = bfbits(val);
        }
      }
    }
  }
}

__global__ __launch_bounds__(256, 2)
void gemm_out(const unsigned short* __restrict__ At, const float* __restrict__ Bw,
              const float* __restrict__ bias, float* __restrict__ Cv) {
  const int K = 1024, N = 1024;
  __shared__ __align__(16) unsigned short As[64 * 64];
  __shared__ __align__(16) unsigned short Bs[128 * 64];
  const int bid = blockIdx.x;
  const int lbid = (bid & 7) * 64 + (bid >> 3);
  const int mb = lbid >> 3, nb = lbid & 7;
  const int tid = threadIdx.x;
  const int lane = tid & 63, w = tid >> 6;
  const int qc = lane & 15, g = lane >> 4;
  f32x4 acc[4][2] = {};

  for (int kt = 0; kt < 16; ++kt) {
    __syncthreads();
#pragma unroll
    for (int i = 0; i < 6; ++i) {
      const int chunk = tid + (i << 8);
      if (i < 2) {
        const int r = chunk >> 3, c8 = chunk & 7;
        const int slot = c8 ^ (r & 7);
        uint4 pa = *(const uint4*)(At + (size_t)(mb * 64 + r) * K + (kt << 6) + (c8 << 3));
        *(uint4*)&As[(r << 6) + (slot << 3)] = pa;
      } else {
        const int cb = chunk - 512;
        const int r = cb >> 3, c8 = cb & 7;
        const int slot = c8 ^ (r & 7);
        const float* srcB = Bw + (size_t)(nb * 128 + r) * K + (kt << 6) + (c8 << 3);
        float4 b0 = *(const float4*)srcB;
        float4 b1 = *(const float4*)(srcB + 4);
        B8 pb;
        pb.u[0] = pk2(b0.x, b0.y); pb.u[1] = pk2(b0.z, b0.w);
        pb.u[2] = pk2(b1.x, b1.y); pb.u[3] = pk2(b1.z, b1.w);
        *(uint4*)&Bs[(r << 6) + (slot << 3)] = pb.u4;
      }
    }
    __syncthreads();

    B8 af[4][2], bfr[2][2];
#pragma unroll
    for (int mi = 0; mi < 4; ++mi)
#pragma unroll
      for (int kk = 0; kk < 2; ++kk) {
        const int row = mi * 16 + qc;
        const int slot = ((kk << 2) + g) ^ (row & 7);
        af[mi][kk].u4 = *(const uint4*)&As[(row << 6) + (slot << 3)];
      }
#pragma unroll
    for (int ni = 0; ni < 2; ++ni)
#pragma unroll
      for (int kk = 0; kk < 2; ++kk) {
        const int row = w * 32 + ni * 16 + qc;
        const int slot = ((kk << 2) + g) ^ (row & 7);
        bfr[ni][kk].u4 = *(const uint4*)&Bs[(row << 6) + (slot << 3)];
      }
#pragma unroll
    for (int kk = 0; kk < 2; ++kk)
#pragma unroll
      for (int mi = 0; mi < 4; ++mi)
#pragma unroll
        for (int ni = 0; ni < 2; ++ni)
          acc[mi][ni] = mfma_bf16(af[mi][kk].v, bfr[ni][kk].v, acc[mi][ni]);
  }

#pragma unroll
  for (int ni = 0; ni < 2; ++ni) {
    const int col = nb * 128 + w * 32 + ni * 16 + qc;
    const float bv = bias[col];
#pragma unroll
    for (int mi = 0; mi < 4; ++mi) {
#pragma unroll
      for (int r = 0; r < 4; ++r) {
        const int row = mb * 64 + mi * 16 + g * 4 + r;
        Cv[(size_t)row * N + col] = acc[mi][ni][r] + bv;
      }
    }
  }
}

// ---------------------------------------------------------------------------
// Causal flash attention + ALiBi (unchanged from r5/r6, passing).
// ---------------------------------------------------------------------------
__global__ __launch_bounds__(256, 4)
void flash_alibi(const unsigned short* __restrict__ Qp,
                 const unsigned short* __restrict__ Kp,
                 const unsigned short* __restrict__ Vt,
                 unsigned short* __restrict__ At) {
  const int S = 2048, Dm = 1024;
  const int bid = blockIdx.x;
  const int z = bid >> 5, y = bid & 31;
  const int s = (y + z) & 31;
  const int h = z & 15, b = z >> 4;
  const int tid = threadIdx.x, lane = tid & 63, w = tid >> 6;
  const int qc = lane & 15, g = lane >> 4;
  const int q0 = s * 64 + w * 16;
  const int qcol = q0 + qc;
  const float slope = exp2f(-(float)(h + 1));
  const float L2E = 1.44269504f;
  const float ls1 = L2E * slope;
  const float THR = 11.54f;
  const size_t bS = (size_t)b * S;
  const int hoff = h * 64;
  const int ntile = s + 1;

  __shared__ __align__(16) unsigned short Ks[64 * 64];
  __shared__ __align__(16) unsigned short Vs[64 * 64];

  B8 qf[2];
  {
    const unsigned short* qa = Qp + (bS + qcol) * Dm + hoff + g * 8;
    qf[0].u4 = *(const uint4*)qa; qf[1].u4 = *(const uint4*)(qa + 32);
  }

  const int srow = tid >> 2;
  const int sg0 = (tid & 3) * 2;
  const int ssw = srow & 7;
  const unsigned short* kg0 = Kp + (bS + srow) * Dm + hoff + sg0 * 8;
  const unsigned short* vg0 = Vt + (((size_t)((b * 16 + h) * 64 + srow)) << 11) + sg0 * 8;
  unsigned short* kw0 = &Ks[srow * 64 + ((sg0 ^ ssw) << 3)];
  unsigned short* kw1 = &Ks[srow * 64 + (((sg0 + 1) ^ ssw) << 3)];
  unsigned short* vw0 = &Vs[srow * 64 + ((sg0 ^ ssw) << 3)];
  unsigned short* vw1 = &Vs[srow * 64 + (((sg0 + 1) ^ ssw) << 3)];
  uint4 krA, krB, vrA, vrB;

#define SLOAD(TT) do {                                                         \
    const unsigned short* kp_ = kg0 + (((size_t)(TT)) << 6) * Dm;              \
    krA = *(const uint4*)kp_; krB = *(const uint4*)(kp_ + 8);                  \
    const unsigned short* vp_ = vg0 + ((TT) << 6);                             \
    vrA = *(const uint4*)vp_; vrB = *(const uint4*)(vp_ + 8);                  \
  } while (0)
#define SWRITE() do {                                                          \
    *(uint4*)kw0 = krA; *(uint4*)kw1 = krB;                                    \
    *(uint4*)vw0 = vrA; *(uint4*)vw1 = vrB;                                    \
  } while (0)

  const int sw = qc & 7;
  const unsigned short* krd0 = &Ks[qc * 64 + ((g ^ sw) << 3)];
  const unsigned short* krd1 = &Ks[qc * 64 + (((g ^ sw) ^ 4) << 3)];
  const unsigned short* vrd[4];
#pragma unroll
  for (int j = 0; j < 4; ++j)
    vrd[j] = &Vs[qc * 64 + ((((2 * j) + (g >> 1)) ^ sw) << 3) + (g & 1) * 4];

  f32x4 acc[4] = {};
  float m_run = 0.f, l_run = 0.f;
  const float abq = slope * (float)(g * 4 - qcol);

#define FRAGX(KV0, MASKED) do {                                                \
    const float kv0f = (float)(KV0);                                           \
    f32x4 sc_[4] = {};                                                         \
    _Pragma("unroll")                                                          \
    for (int f_ = 0; f_ < 4; ++f_) {                                           \
      B8 k0_, k1_;                                                             \
      k0_.u4 = *(const uint4*)(krd0 + f_ * 1024);                              \
      k1_.u4 = *(const uint4*)(krd1 + f_ * 1024);                              \
      sc_[f_] = mfma_bf16(k0_.v, qf[0].v, sc_[f_]);                            \
      sc_[f_] = mfma_bf16(k1_.v, qf[1].v, sc_[f_]);                            \
    }                                                                          \
    const float cb_ = (fmaf(slope, kv0f, abq) - m_run) * L2E;                  \
    float ein_[4][4]; float emax_ = -1e30f;                                    \
    _Pragma("unroll")                                                          \
    for (int f_ = 0; f_ < 4; ++f_) {                                           \
      const float cf_ = cb_ + (float)(16 * f_) * ls1;                          \
      _Pragma("unroll")                                                        \
      for (int r_ = 0; r_ < 4; ++r_) {                                         \
        float e_ = fmaf(sc_[f_][r_], L2E, cf_ + (float)r_ * ls1);              \
        if (MASKED) {                                                          \
          const int kv_ = (KV0) + f_ * 16 + g * 4 + r_;                        \
          if (kv_ > qcol) e_ = -1e30f;                                         \
        }                                                                      \
        ein_[f_][r_] = e_; emax_ = fmaxf(emax_, e_);                           \
      }                                                                        \
    }                                                                          \
    if (!__all(emax_ <= THR)) {                                                \
      float er_ = fmaxf(emax_, __shfl_xor(emax_, 16));                         \
      er_ = fmaxf(er_, __shfl_xor(er_, 32));                                   \
      er_ = fmaxf(er_, 0.f);                                                   \
      m_run += er_ * 0.69314718f;                                              \
      const float sfac_ = EXP2F(-er_);                                         \
      l_run *= sfac_;                                                          \
      _Pragma("unroll") for (int n_ = 0; n_ < 4; ++n_) acc[n_] = acc[n_] * sfac_; \
      _Pragma("unroll") for (int f_ = 0; f_ < 4; ++f_)                         \
        _Pragma("unroll") for (int r_ = 0; r_ < 4; ++r_) ein_[f_][r_] -= er_;  \
    }                                                                          \
    B8 pf0_, pf1_; float lsum_ = 0.f;                                          \
    _Pragma("unroll")                                                          \
    for (int f_ = 0; f_ < 4; ++f_) {                                           \
      _Pragma("unroll")                                                        \
      for (int r_ = 0; r_ < 4; ++r_) {                                         \
        const float p_ = EXP2F(ein_[f_][r_]);                                  \
        lsum_ += p_;                                                           \
        if (f_ == 0)      pf0_.v[r_]     = (__bf16)p_;                         \
        else if (f_ == 1) pf0_.v[4 + r_] = (__bf16)p_;                         \
        else if (f_ == 2) pf1_.v[r_]     = (__bf16)p_;                         \
        else              pf1_.v[4 + r_] = (__bf16)p_;                         \
      }                                                                        \
    }                                                                          \
    l_run += lsum_;                                                            \
    _Pragma("unroll")                                                          \
    for (int n_ = 0; n_ < 4; ++n_) {                                           \
      B8 v0_, v1_;                                                             \
      uint2 a0_ = *(const uint2*)(vrd[0] + n_ * 1024);                         \
      uint2 a1_ = *(const uint2*)(vrd[1] + n_ * 1024);                         \
      uint2 a2_ = *(const uint2*)(vrd[2] + n_ * 1024);                         \
      uint2 a3_ = *(const uint2*)(vrd[3] + n_ * 1024);                         \
      v0_.u[0] = a0_.x; v0_.u[1] = a0_.y;                                      \
      v0_.u[2] = a1_.x; v0_.u[3] = a1_.y;                                      \
      v1_.u[0] = a2_.x; v1_.u[1] = a2_.y;                                      \
      v1_.u[2] = a3_.x; v1_.u[3] = a3_.y;                                      \
      acc[n_] = mfma_bf16(v0_.v, pf0_.v, acc[n_]);                             \
      acc[n_] = mfma_bf16(v1_.v, pf1_.v, acc[n_]);                             \
    }                                                                          \
  } while (0)

  SLOAD(0);
  SWRITE();
  __syncthreads();

  for (int t = 0; t < ntile - 1; ++t) {
    SLOAD(t + 1);
    FRAGX(t << 6, 0);
    __syncthreads();
    SWRITE();
    __syncthreads();
  }
  FRAGX((ntile - 1) << 6, 1);

  float lt = l_run + __shfl_xor(l_run, 16);
  lt += __shfl_xor(lt, 32);
  const float ri = 1.0f / lt;
  unsigned short* ob = At + (bS + qcol) * Dm + hoff;
#pragma unroll
  for (int n = 0; n < 4; ++n) {
    B4 ov;
    ov.v[0] = (__bf16)(acc[n][0] * ri);
    ov.v[1] = (__bf16)(acc[n][1] * ri);
    ov.v[2] = (__bf16)(acc[n][2] * ri);
    ov.v[3] = (__bf16)(acc[n][3] * ri);
    *(uint2*)(ob + n * 16 + g * 4) = ov.u2;
  }
}

extern "C" void kernel_launch(void* const* d_in, const int* in_sizes, int n_in,
                              void* d_out, int out_size, void* d_ws, size_t ws_size,
                              hipStream_t stream) {
  const float* q    = (const float*)d_in[0];
  const float* k    = (const float*)d_in[1];
  const float* v    = (const float*)d_in[2];
  const float* wq_w = (const float*)d_in[4];
  const float* wq_b = (const float*)d_in[5];
  const float* wk_w = (const float*)d_in[6];
  const float* wk_b = (const float*)d_in[7];
  const float* wv_w = (const float*)d_in[8];
  const float* wv_b = (const float*)d_in[9];
  const float* ow   = (const float*)d_in[10];
  const float* ob   = (const float*)d_in[11];
  float* out = (float*)d_out;

  char* ws = (char*)d_ws;
  unsigned short* Qp = (unsigned short*)(ws);                  // 8MB [4096,1024]
  unsigned short* Kp = (unsigned short*)(ws + (8u << 20));     // 8MB
  unsigned short* Vt = (unsigned short*)(ws + (16u << 20));    // 8MB [B,H,64,2048]
  unsigned short* At = (unsigned short*)(ws + (24u << 20));    // 8MB [4096,1024]

  dim3 blk(256);
  if (ws_size >= (64ull << 20)) {
    unsigned short* cvt = (unsigned short*)(ws + (32u << 20)); // 32MB contiguous
    unsigned short* qb  = cvt;                                  // 2^22 elems
    unsigned short* kb  = cvt + (1u << 22);
    unsigned short* vb  = cvt + (2u << 22);
    unsigned short* wqb = cvt + (3u << 22);
    unsigned short* wkb = wqb + (1u << 20);
    unsigned short* wvb = wkb + (1u << 20);
    unsigned short* wob = wvb + (1u << 20);
    cvt_all<<<8192, blk, 0, stream>>>(q, k, v, wq_w, wk_w, wv_w, ow, cvt);
    gemm_qkv_b<<<768, blk, 0, stream>>>(qb, kb, vb, wqb, wkb, wvb,
                                        wq_b, wk_b, wv_b, Qp, Kp, Vt);
    flash_alibi<<<1024, blk, 0, stream>>>(Qp, Kp, Vt, At);
    gemm_out_b<<<512, blk, 0, stream>>>(At, wob, ob, out);
  } else {
    gemm_qkv<<<768, blk, 0, stream>>>(q, k, v, wq_w, wk_w, wv_w,
                                      wq_b, wk_b, wv_b, Qp, Kp, Vt);
    flash_alibi<<<1024, blk, 0, stream>>>(Qp, Kp, Vt, At);
    gemm_out<<<512, blk, 0, stream>>>(At, ow, ob, out);
  }
}